// Round 5
// baseline (1345.226 us; speedup 1.0000x reference)
//
#include <hip/hip_runtime.h>
#include <hip/hip_bf16.h>

typedef short bf16x8 __attribute__((ext_vector_type(8)));   // 8 bf16 in 4 VGPRs
typedef float f32x4  __attribute__((ext_vector_type(4)));   // MFMA C/D frag

#define MFMA16(a,b,c) __builtin_amdgcn_mfma_f32_16x16x32_bf16((a),(b),(c),0,0,0)

typedef __attribute__((address_space(3))) unsigned int       lds_u32;
typedef const __attribute__((address_space(1))) unsigned int g_u32;

static constexpr int SEQ = 2048;
static constexpr int DM  = 2048;
static constexpr int NH  = 16;
static constexpr int DH  = 128;
static constexpr int BAT = 4;
static constexpr int BH  = BAT * NH;      // 64
static constexpr int MROWS = BAT * SEQ;   // 8192

// ---------------------------------------------------------------------------
// fp32 -> bf16 elementwise (8 elems/thread, 16B loads, 16B stores)
// ---------------------------------------------------------------------------
__global__ __launch_bounds__(256)
void cvt_bf16(const float* __restrict__ in, __hip_bfloat16* __restrict__ out)
{
    int i = blockIdx.x * 256 + threadIdx.x;
    const float4* p = (const float4*)in + (size_t)i * 2;
    float4 a = p[0], b = p[1];
    __hip_bfloat16 t[8];
    t[0]=__float2bfloat16(a.x); t[1]=__float2bfloat16(a.y);
    t[2]=__float2bfloat16(a.z); t[3]=__float2bfloat16(a.w);
    t[4]=__float2bfloat16(b.x); t[5]=__float2bfloat16(b.y);
    t[6]=__float2bfloat16(b.z); t[7]=__float2bfloat16(b.w);
    *(uint4*)(out + (size_t)i * 8) = *(uint4*)t;
}

// ---------------------------------------------------------------------------
// fp32 [K][N] -> bf16 [N][K] transpose-convert, 32x32 LDS tiles
// ---------------------------------------------------------------------------
__global__ __launch_bounds__(256)
void cvt_T(const float* __restrict__ in, __hip_bfloat16* __restrict__ out,
           int K, int N)
{
    __shared__ float t[32][33];
    const int n0 = blockIdx.x * 32, k0 = blockIdx.y * 32;
    const int r = threadIdx.x >> 3, c4 = (threadIdx.x & 7) * 4;
    float4 v = *(const float4*)(in + (size_t)(k0 + r) * N + n0 + c4);
    t[r][c4] = v.x; t[r][c4+1] = v.y; t[r][c4+2] = v.z; t[r][c4+3] = v.w;
    __syncthreads();
    __hip_bfloat16 o[4];
    #pragma unroll
    for (int j = 0; j < 4; ++j) o[j] = __float2bfloat16(t[c4 + j][r]);
    *(uint2*)(out + (size_t)(n0 + r) * K + k0 + c4) = *(uint2*)o;
}

// ---------------------------------------------------------------------------
// Stage one half-tile (128 rows x 64 k, bf16) into LDS via global_load_lds.
// LDS dest is LINEAR; XOR-swizzle (chunk' = k8 ^ (row&7)) applied by
// pre-swizzling the per-lane GLOBAL source address (rule #21).
// ---------------------------------------------------------------------------
__device__ __forceinline__
void stage_half(const __hip_bfloat16* __restrict__ g, int row0, int k0, int K,
                __hip_bfloat16* l, int tid)
{
    #pragma unroll
    for (int pass = 0; pass < 2; ++pass) {
        int c   = pass * 512 + tid;              // chunk index within half
        int row = c >> 3;                        // 0..127
        int k8  = (c & 7) ^ (row & 7);           // inverse-swizzled k-octet
        const __hip_bfloat16* gp = g + (size_t)(row0 + row) * K + k0 + k8 * 8;
        __hip_bfloat16* lp = l + (size_t)(pass * 512 + (tid & ~63)) * 8;
        __builtin_amdgcn_global_load_lds((g_u32*)gp, (lds_u32*)lp, 16, 0, 0);
    }
}

// ---------------------------------------------------------------------------
// 256x256-tile 8-phase GEMM (T1+T2+T3+T4+T5), BK=64, 8 waves (2M x 4N),
// 512 threads, 128 KiB LDS (2 tile dbuf x (A,B) x [256][64] bf16, XOR-swz).
// (unchanged from round 1)
// ---------------------------------------------------------------------------
template<int MODE>
__global__ __launch_bounds__(512)
void gemm_bt256(const __hip_bfloat16* __restrict__ A,
                const __hip_bfloat16* __restrict__ Bt,
                const float* __restrict__ bias,
                void* __restrict__ outp, int K)
{
    __shared__ __hip_bfloat16 As[2][16384];   // [buf][row*8 + k8] chunks
    __shared__ __hip_bfloat16 Bs[2][16384];

    const int tid  = threadIdx.x;
    const int wave = tid >> 6, lane = tid & 63;
    const int quad = lane >> 4, l16 = lane & 15;
    const int wr = wave >> 2, wc = wave & 3;   // 2 x 4 wave grid

    const int nwg = gridDim.x * gridDim.y;
    int bid = blockIdx.y * gridDim.x + blockIdx.x;
    bid = (bid & 7) * (nwg >> 3) + (bid >> 3);
    const int n0 = (bid % gridDim.x) * 256;
    const int m0 = (bid / gridDim.x) * 256;

    const int NT = K >> 6;                     // 64-wide K tiles
    const int swz = l16 & 7;                   // per-lane read-side XOR

    f32x4 acc[8][4] = {};

    stage_half(A,  m0,        0,  K, &As[0][0],    tid);
    stage_half(A,  m0 + 128,  0,  K, &As[0][8192], tid);
    stage_half(Bt, n0,        0,  K, &Bs[0][0],    tid);
    stage_half(Bt, n0 + 128,  0,  K, &Bs[0][8192], tid);
    stage_half(Bt, n0,        64, K, &Bs[1][0],    tid);
    stage_half(Bt, n0 + 128,  64, K, &Bs[1][8192], tid);
    asm volatile("s_waitcnt vmcnt(4)" ::: "memory");
    __builtin_amdgcn_s_barrier();

    for (int t = 0; t < NT; ++t) {
        const int cur = t & 1;
        const char* Ab = (const char*)&As[cur][0];
        const char* Bb = (const char*)&Bs[cur][0];
        bf16x8 afl[4][2], afh[4][2], bf[4][2];

        // ================= phase 1 =================
        #pragma unroll
        for (int i = 0; i < 4; ++i)
            #pragma unroll
            for (int kk = 0; kk < 2; ++kk)
                afl[i][kk] = *(const bf16x8*)(Ab + (wr*128 + i*16 + l16)*128
                              + ((((kk<<2)|quad) ^ swz) << 4));
        #pragma unroll
        for (int j = 0; j < 2; ++j)
            #pragma unroll
            for (int kk = 0; kk < 2; ++kk)
                bf[j][kk] = *(const bf16x8*)(Bb + (wc*64 + j*16 + l16)*128
                              + ((((kk<<2)|quad) ^ swz) << 4));
        if (t + 1 < NT)
            stage_half(A, m0, (t+1)*64, K, &As[cur^1][0], tid);
        __builtin_amdgcn_s_barrier();
        asm volatile("s_waitcnt lgkmcnt(0)" ::: "memory");
        __builtin_amdgcn_s_setprio(1);
        #pragma unroll
        for (int i = 0; i < 4; ++i)
            #pragma unroll
            for (int j = 0; j < 2; ++j) {
                acc[i][j] = MFMA16(afl[i][0], bf[j][0], acc[i][j]);
                acc[i][j] = MFMA16(afl[i][1], bf[j][1], acc[i][j]);
            }
        __builtin_amdgcn_s_setprio(0);
        __builtin_amdgcn_s_barrier();

        // ================= phase 2 =================
        #pragma unroll
        for (int j = 2; j < 4; ++j)
            #pragma unroll
            for (int kk = 0; kk < 2; ++kk)
                bf[j][kk] = *(const bf16x8*)(Bb + (wc*64 + j*16 + l16)*128
                              + ((((kk<<2)|quad) ^ swz) << 4));
        if (t + 1 < NT)
            stage_half(A, m0 + 128, (t+1)*64, K, &As[cur^1][8192], tid);
        __builtin_amdgcn_s_barrier();
        asm volatile("s_waitcnt lgkmcnt(0)" ::: "memory");
        __builtin_amdgcn_s_setprio(1);
        #pragma unroll
        for (int i = 0; i < 4; ++i)
            #pragma unroll
            for (int j = 2; j < 4; ++j) {
                acc[i][j] = MFMA16(afl[i][0], bf[j][0], acc[i][j]);
                acc[i][j] = MFMA16(afl[i][1], bf[j][1], acc[i][j]);
            }
        __builtin_amdgcn_s_setprio(0);
        __builtin_amdgcn_s_barrier();

        // ================= phase 3 =================
        #pragma unroll
        for (int i = 0; i < 4; ++i)
            #pragma unroll
            for (int kk = 0; kk < 2; ++kk)
                afh[i][kk] = *(const bf16x8*)(Ab + (wr*128 + (4+i)*16 + l16)*128
                              + ((((kk<<2)|quad) ^ swz) << 4));
        if (t + 2 < NT)
            stage_half(Bt, n0, (t+2)*64, K, &Bs[cur][0], tid);
        __builtin_amdgcn_s_barrier();
        asm volatile("s_waitcnt lgkmcnt(0)" ::: "memory");
        __builtin_amdgcn_s_setprio(1);
        #pragma unroll
        for (int i = 0; i < 4; ++i)
            #pragma unroll
            for (int j = 0; j < 2; ++j) {
                acc[4+i][j] = MFMA16(afh[i][0], bf[j][0], acc[4+i][j]);
                acc[4+i][j] = MFMA16(afh[i][1], bf[j][1], acc[4+i][j]);
            }
        __builtin_amdgcn_s_setprio(0);
        __builtin_amdgcn_s_barrier();

        // ================= phase 4 =================
        if (t + 2 < NT)
            stage_half(Bt, n0 + 128, (t+2)*64, K, &Bs[cur][8192], tid);
        asm volatile("s_waitcnt vmcnt(4)" ::: "memory");  // (t+1) halves landed
        __builtin_amdgcn_s_barrier();
        __builtin_amdgcn_s_setprio(1);
        #pragma unroll
        for (int i = 0; i < 4; ++i)
            #pragma unroll
            for (int j = 2; j < 4; ++j) {
                acc[4+i][j] = MFMA16(afh[i][0], bf[j][0], acc[4+i][j]);
                acc[4+i][j] = MFMA16(afh[i][1], bf[j][1], acc[4+i][j]);
            }
        __builtin_amdgcn_s_setprio(0);
        __builtin_amdgcn_s_barrier();
    }

    // ---- epilogue: D row = quad*4+r, col = l16 (m89/m91 layout) ----
    #pragma unroll
    for (int i = 0; i < 8; ++i)
        #pragma unroll
        for (int j = 0; j < 4; ++j) {
            int col = n0 + wc * 64 + j * 16 + l16;
            float bs = bias[col];
            #pragma unroll
            for (int r = 0; r < 4; ++r) {
                int row = m0 + wr * 128 + i * 16 + quad * 4 + r;
                float v = acc[i][j][r] + bs;
                if (MODE == 0) {
                    int which = col >> 11, h = (col >> 7) & 15, d = col & 127;
                    int bb = row >> 11, s = row & 2047;
                    __hip_bfloat16* o = (__hip_bfloat16*)outp;
                    size_t idx;
                    if (which == 2)   // V transposed: [BH][Dh][S]
                        idx = 2 * (size_t)BH * SEQ * DH +
                              ((size_t)(bb * NH + h) * DH + d) * SEQ + s;
                    else
                        idx = (size_t)which * BH * SEQ * DH +
                              ((size_t)(bb * NH + h) * SEQ + s) * DH + d;
                    o[idx] = __float2bfloat16(v);
                } else {
                    ((float*)outp)[(size_t)row * DM + col] = v;
                }
            }
        }
}

// ---------------------------------------------------------------------------
// Causal flash attention, 8-wave / 128 q-rows per block.
// Q,K bf16 [BH][S][Dh]; V bf16 [BH][Dh][S] (pre-transposed).
// 512 threads, 8 waves x 16 q rows, KVBLK=64.
// LDS = Ks 16KB + Vs 16KB = 32 KB -> 4 blocks/CU (32 waves, wave-capped);
// Ps (128x64, swizzled) ALIASES Ks (dead after QK^T); extra barrier guards
// the overwrite.  __launch_bounds__(512,8) pins VGPR<=64 (occupancy cliff
// at 65).  XCD-aware remap: each XCD owns 8 heads -> K/V L2-resident.
// Defer-max (T13, THR=8) skips the O-rescale on most tiles.
// ---------------------------------------------------------------------------
__global__ __launch_bounds__(512, 8)
void attn_kernel(const __hip_bfloat16* __restrict__ q,
                 const __hip_bfloat16* __restrict__ k,
                 const __hip_bfloat16* __restrict__ v,
                 __hip_bfloat16* __restrict__ o)
{
    __shared__ __hip_bfloat16 Ks[4 * 64 * 32];    // 16 KB: [kk][64][32]; P alias
    __shared__ __hip_bfloat16 Vs[2 * 128 * 32];   // 16 KB: [f2][128][32]

    const int tid  = threadIdx.x;
    const int wave = tid >> 6, lane = tid & 63;
    const int quad = lane >> 4, l16 = lane & 15;

    // XCD-aware remap (bijective, 1024 blocks = 8 XCD x 8 bh x 16 qtiles):
    // HW assigns XCD = bid % 8; give each XCD a contiguous bh range so its
    // K/V working set (1-2 MB) stays L2-resident.  Heavy q-tiles first.
    const int bid = blockIdx.y * gridDim.x + blockIdx.x;
    const int xcd = bid & 7, j = bid >> 3;        // j in 0..127
    const int bh  = xcd * 8 + (j >> 4);
    const int qt  = 15 - (j & 15);
    const int q0 = qt * 128;
    const int nkt = 2 * qt + 2;                   // k-tiles covering q0+127
    const size_t base = (size_t)bh * SEQ * DH;    // same elem count for V^T
    const float scale = 0.08838834764831845f;     // 1/sqrt(128)

    // Q fragments in registers, prescaled: A[m=l16][k=quad*8+j]
    bf16x8 qf[4];
    #pragma unroll
    for (int kk = 0; kk < 4; ++kk) {
        bf16x8 raw = *(const bf16x8*)(
            q + base + (size_t)(q0 + wave * 16 + l16) * DH + kk * 32 + quad * 8);
        #pragma unroll
        for (int jj = 0; jj < 8; ++jj) {
            __hip_bfloat16 h = ((const __hip_bfloat16*)&raw)[jj];
            ((__hip_bfloat16*)&qf[kk])[jj] =
                __float2bfloat16(__bfloat162float(h) * scale);
        }
    }

    float m_run[4], l_run[4];
    f32x4 oacc[8] = {};
    #pragma unroll
    for (int r = 0; r < 4; ++r) { m_run[r] = -1e30f; l_run[r] = 0.f; }

    const int wmax = q0 + wave * 16 + 15;         // last unmasked row of wave

    for (int kt = 0; kt < nkt; ++kt) {
        __syncthreads();   // prior iter's Ks(P)/Vs reads done
        // ---- DMA-stage K tile (4 slabs [64][32]) and V^T tile (2 slabs) ----
        {
            const __hip_bfloat16* kbase = k + base + (size_t)(kt * 64) * DH;
            const __hip_bfloat16* vbase = v + base + kt * 64;
            #pragma unroll
            for (int p = 0; p < 2; ++p) {
                int c = p * 512 + tid;                 // chunk id = LDS/16B
                int kk = c >> 8, krow = (c >> 2) & 63, h = c & 3;
                const __hip_bfloat16* gk =
                    kbase + (size_t)krow * DH + kk * 32 + h * 8;
                __hip_bfloat16* lk = Ks + (size_t)(p * 512 + (tid & ~63)) * 8;
                __builtin_amdgcn_global_load_lds((g_u32*)gk, (lds_u32*)lk, 16, 0, 0);
                int f2 = c >> 9, d = (c >> 2) & 127;
                const __hip_bfloat16* gv =
                    vbase + (size_t)d * SEQ + f2 * 32 + h * 8;
                __hip_bfloat16* lv = Vs + (size_t)(p * 512 + (tid & ~63)) * 8;
                __builtin_amdgcn_global_load_lds((g_u32*)gv, (lds_u32*)lv, 16, 0, 0);
            }
        }
        __syncthreads();   // staging visible (vmcnt drain + barrier)

        const bool active = (kt * 64 <= wmax);
        float pv[4][4];

        if (active) {
            // ---- S = (Q*scale) K^T : 16 q rows x 64 k cols per wave ----
            f32x4 sacc[4] = {};
            __builtin_amdgcn_s_setprio(1);
            #pragma unroll
            for (int kk = 0; kk < 4; ++kk)
                #pragma unroll
                for (int f = 0; f < 4; ++f) {
                    bf16x8 b = *(const bf16x8*)(
                        &Ks[kk * 2048 + (f * 16 + l16) * 32 + quad * 8]);
                    sacc[f] = MFMA16(qf[kk], b, sacc[f]);
                }
            __builtin_amdgcn_s_setprio(0);

            // ---- causal mask (diagonal tiles only) + online softmax ----
            const int qrow = q0 + wave * 16 + quad * 4;
            if (kt * 64 + 63 > q0 + wave * 16) {
                #pragma unroll
                for (int f = 0; f < 4; ++f)
                    #pragma unroll
                    for (int r = 0; r < 4; ++r) {
                        int kg = kt * 64 + f * 16 + l16;
                        if (kg > qrow + r) sacc[f][r] = -1e30f;
                    }
            }
            float mloc[4] = {-1e30f, -1e30f, -1e30f, -1e30f};
            #pragma unroll
            for (int f = 0; f < 4; ++f)
                #pragma unroll
                for (int r = 0; r < 4; ++r)
                    mloc[r] = fmaxf(mloc[r], sacc[f][r]);
            #pragma unroll
            for (int off = 1; off < 16; off <<= 1)
                #pragma unroll
                for (int r = 0; r < 4; ++r)
                    mloc[r] = fmaxf(mloc[r], __shfl_xor(mloc[r], off, 64));

            // ---- defer-max (T13): rescale only when max grew > THR ----
            bool ok = true;
            #pragma unroll
            for (int r = 0; r < 4; ++r) ok &= (mloc[r] <= m_run[r] + 8.f);
            if (!__all(ok)) {
                float alpha[4];
                #pragma unroll
                for (int r = 0; r < 4; ++r) {
                    float mn = fmaxf(m_run[r], mloc[r]);
                    alpha[r] = __expf(m_run[r] - mn);
                    m_run[r] = mn;
                    l_run[r] *= alpha[r];
                }
                #pragma unroll
                for (int dt = 0; dt < 8; ++dt)
                    #pragma unroll
                    for (int r = 0; r < 4; ++r) oacc[dt][r] *= alpha[r];
            }

            float lloc[4] = {0.f, 0.f, 0.f, 0.f};
            #pragma unroll
            for (int f = 0; f < 4; ++f)
                #pragma unroll
                for (int r = 0; r < 4; ++r) {
                    float pe = __expf(sacc[f][r] - m_run[r]);
                    pv[f][r] = pe;
                    lloc[r] += pe;
                }
            #pragma unroll
            for (int off = 1; off < 16; off <<= 1)
                #pragma unroll
                for (int r = 0; r < 4; ++r)
                    lloc[r] += __shfl_xor(lloc[r], off, 64);
            #pragma unroll
            for (int r = 0; r < 4; ++r) l_run[r] += lloc[r];
        }

        __syncthreads();   // ALL waves' QK^T reads of Ks done before P alias

        if (active) {
            // ---- P (C-layout) -> swizzled alias region (wave-private rows):
            //      elem = row*64 + (chunk ^ (row&7))*8 + (l16&7),
            //      chunk = f*2 + (l16>>3) ----
            #pragma unroll
            for (int f = 0; f < 4; ++f)
                #pragma unroll
                for (int r = 0; r < 4; ++r) {
                    int row = wave * 16 + quad * 4 + r;
                    int ch  = (f * 2 + (l16 >> 3)) ^ (row & 7);
                    Ks[row * 64 + ch * 8 + (l16 & 7)] =
                        __float2bfloat16(pv[f][r]);
                }
            // same-wave RAW covered by lgkmcnt; Ps rows are wave-private

            // ---- O += P V ----
            __builtin_amdgcn_s_setprio(1);
            #pragma unroll
            for (int f2 = 0; f2 < 2; ++f2) {
                int prow = wave * 16 + l16;
                bf16x8 a = *(const bf16x8*)(
                    &Ks[prow * 64 + (((f2 << 2) | quad) ^ (l16 & 7)) * 8]);
                #pragma unroll
                for (int dt = 0; dt < 8; ++dt) {
                    bf16x8 b = *(const bf16x8*)(
                        &Vs[f2 * 4096 + (dt * 16 + l16) * 32 + quad * 8]);
                    oacc[dt] = MFMA16(a, b, oacc[dt]);
                }
            }
            __builtin_amdgcn_s_setprio(0);
        }
    }

    // epilogue: normalize and store O (bf16) into [B][S][D_MODEL]
    const int bb = bh >> 4, h = bh & 15;
    #pragma unroll
    for (int dt = 0; dt < 8; ++dt)
        #pragma unroll
        for (int r = 0; r < 4; ++r) {
            int srow = q0 + wave * 16 + quad * 4 + r;
            float val = oacc[dt][r] / l_run[r];
            o[((size_t)(bb * SEQ + srow)) * DM + h * DH + dt * 16 + l16] =
                __float2bfloat16(val);
        }
}

// ---------------------------------------------------------------------------
extern "C" void kernel_launch(void* const* d_in, const int* in_sizes, int n_in,
                              void* d_out, int out_size, void* d_ws, size_t ws_size,
                              hipStream_t stream)
{
    const float* x     = (const float*)d_in[0];   // [4,2048,2048] fp32
    const float* w_qkv = (const float*)d_in[1];   // [2048,6144]   fp32
    const float* b_qkv = (const float*)d_in[2];   // [6144]        fp32
    const float* w_out = (const float*)d_in[3];   // [2048,2048]   fp32
    const float* b_out = (const float*)d_in[4];   // [2048]        fp32
    float* out = (float*)d_out;                   // [4,2048,2048] fp32
    __hip_bfloat16* ws = (__hip_bfloat16*)d_ws;

    constexpr size_t NX    = (size_t)MROWS * DM;        // 16.78M
    constexpr size_t NWQKV = (size_t)DM * 3 * DM;       // 12.58M
    constexpr size_t NWOUT = (size_t)DM * DM;           //  4.19M
    constexpr size_t T     = (size_t)BH * SEQ * DH;     // 16.78M

    __hip_bfloat16* xb    = ws;                         // reused as op later
    __hip_bfloat16* wqkvT = ws + NX;
    __hip_bfloat16* woutT = ws + NX + NWQKV;
    __hip_bfloat16* qkv   = ws + NX + NWQKV + NWOUT;    // q | k | v^T
    __hip_bfloat16* op    = xb;                         // [B][S][D] bf16

    // 0) precision/layout prep (memory-bound, ~35 us total)
    cvt_bf16<<<NX / (8 * 256), 256, 0, stream>>>(x, xb);
    cvt_T<<<dim3(3 * DM / 32, DM / 32), 256, 0, stream>>>(w_qkv, wqkvT, DM, 3 * DM);
    cvt_T<<<dim3(DM / 32, DM / 32), 256, 0, stream>>>(w_out, woutT, DM, DM);

    // 1) fused QKV projection -> q,k [BH][S][Dh], v [BH][Dh][S]
    gemm_bt256<0><<<dim3(3 * DM / 256, MROWS / 256), 512, 0, stream>>>(
        xb, wqkvT, b_qkv, qkv, DM);
    // 2) causal flash attention (128 q-rows / block, 8 waves, XCD-grouped)
    attn_kernel<<<dim3(SEQ / 128, BH), 512, 0, stream>>>(
        qkv, qkv + T, qkv + 2 * T, op);
    // 3) output projection -> fp32 d_out
    gemm_bt256<1><<<dim3(DM / 256, MROWS / 256), 512, 0, stream>>>(
        op, woutT, b_out, out, DM);
}

// Round 6
// 677.622 us; speedup vs baseline: 1.9852x; 1.9852x over previous
//
#include <hip/hip_runtime.h>
#include <hip/hip_bf16.h>

typedef short bf16x8 __attribute__((ext_vector_type(8)));   // 8 bf16 in 4 VGPRs
typedef float f32x4  __attribute__((ext_vector_type(4)));   // MFMA C/D frag

#define MFMA16(a,b,c) __builtin_amdgcn_mfma_f32_16x16x32_bf16((a),(b),(c),0,0,0)

typedef __attribute__((address_space(3))) unsigned int       lds_u32;
typedef const __attribute__((address_space(1))) unsigned int g_u32;

static constexpr int SEQ = 2048;
static constexpr int DM  = 2048;
static constexpr int NH  = 16;
static constexpr int DH  = 128;
static constexpr int BAT = 4;
static constexpr int BH  = BAT * NH;      // 64
static constexpr int MROWS = BAT * SEQ;   // 8192

// ---------------------------------------------------------------------------
// fp32 -> bf16 elementwise (8 elems/thread, 16B loads, 16B stores)
// ---------------------------------------------------------------------------
__global__ __launch_bounds__(256)
void cvt_bf16(const float* __restrict__ in, __hip_bfloat16* __restrict__ out)
{
    int i = blockIdx.x * 256 + threadIdx.x;
    const float4* p = (const float4*)in + (size_t)i * 2;
    float4 a = p[0], b = p[1];
    __hip_bfloat16 t[8];
    t[0]=__float2bfloat16(a.x); t[1]=__float2bfloat16(a.y);
    t[2]=__float2bfloat16(a.z); t[3]=__float2bfloat16(a.w);
    t[4]=__float2bfloat16(b.x); t[5]=__float2bfloat16(b.y);
    t[6]=__float2bfloat16(b.z); t[7]=__float2bfloat16(b.w);
    *(uint4*)(out + (size_t)i * 8) = *(uint4*)t;
}

// ---------------------------------------------------------------------------
// fp32 [K][N] -> bf16 [N][K] transpose-convert, 32x32 LDS tiles
// ---------------------------------------------------------------------------
__global__ __launch_bounds__(256)
void cvt_T(const float* __restrict__ in, __hip_bfloat16* __restrict__ out,
           int K, int N)
{
    __shared__ float t[32][33];
    const int n0 = blockIdx.x * 32, k0 = blockIdx.y * 32;
    const int r = threadIdx.x >> 3, c4 = (threadIdx.x & 7) * 4;
    float4 v = *(const float4*)(in + (size_t)(k0 + r) * N + n0 + c4);
    t[r][c4] = v.x; t[r][c4+1] = v.y; t[r][c4+2] = v.z; t[r][c4+3] = v.w;
    __syncthreads();
    __hip_bfloat16 o[4];
    #pragma unroll
    for (int j = 0; j < 4; ++j) o[j] = __float2bfloat16(t[c4 + j][r]);
    *(uint2*)(out + (size_t)(n0 + r) * K + k0 + c4) = *(uint2*)o;
}

// ---------------------------------------------------------------------------
// Stage one half-tile (128 rows x 64 k, bf16) into LDS via global_load_lds.
// LDS dest is LINEAR; XOR-swizzle (chunk' = k8 ^ (row&7)) applied by
// pre-swizzling the per-lane GLOBAL source address (rule #21).
// ---------------------------------------------------------------------------
__device__ __forceinline__
void stage_half(const __hip_bfloat16* __restrict__ g, int row0, int k0, int K,
                __hip_bfloat16* l, int tid)
{
    #pragma unroll
    for (int pass = 0; pass < 2; ++pass) {
        int c   = pass * 512 + tid;              // chunk index within half
        int row = c >> 3;                        // 0..127
        int k8  = (c & 7) ^ (row & 7);           // inverse-swizzled k-octet
        const __hip_bfloat16* gp = g + (size_t)(row0 + row) * K + k0 + k8 * 8;
        __hip_bfloat16* lp = l + (size_t)(pass * 512 + (tid & ~63)) * 8;
        __builtin_amdgcn_global_load_lds((g_u32*)gp, (lds_u32*)lp, 16, 0, 0);
    }
}

// ---------------------------------------------------------------------------
// 256x256-tile 8-phase GEMM (T1+T2+T3+T4+T5), BK=64, 8 waves (2M x 4N),
// 512 threads, 128 KiB LDS (2 tile dbuf x (A,B) x [256][64] bf16, XOR-swz).
// (unchanged from round 1)
// ---------------------------------------------------------------------------
template<int MODE>
__global__ __launch_bounds__(512)
void gemm_bt256(const __hip_bfloat16* __restrict__ A,
                const __hip_bfloat16* __restrict__ Bt,
                const float* __restrict__ bias,
                void* __restrict__ outp, int K)
{
    __shared__ __hip_bfloat16 As[2][16384];   // [buf][row*8 + k8] chunks
    __shared__ __hip_bfloat16 Bs[2][16384];

    const int tid  = threadIdx.x;
    const int wave = tid >> 6, lane = tid & 63;
    const int quad = lane >> 4, l16 = lane & 15;
    const int wr = wave >> 2, wc = wave & 3;   // 2 x 4 wave grid

    const int nwg = gridDim.x * gridDim.y;
    int bid = blockIdx.y * gridDim.x + blockIdx.x;
    bid = (bid & 7) * (nwg >> 3) + (bid >> 3);
    const int n0 = (bid % gridDim.x) * 256;
    const int m0 = (bid / gridDim.x) * 256;

    const int NT = K >> 6;                     // 64-wide K tiles
    const int swz = l16 & 7;                   // per-lane read-side XOR

    f32x4 acc[8][4] = {};

    stage_half(A,  m0,        0,  K, &As[0][0],    tid);
    stage_half(A,  m0 + 128,  0,  K, &As[0][8192], tid);
    stage_half(Bt, n0,        0,  K, &Bs[0][0],    tid);
    stage_half(Bt, n0 + 128,  0,  K, &Bs[0][8192], tid);
    stage_half(Bt, n0,        64, K, &Bs[1][0],    tid);
    stage_half(Bt, n0 + 128,  64, K, &Bs[1][8192], tid);
    asm volatile("s_waitcnt vmcnt(4)" ::: "memory");
    __builtin_amdgcn_s_barrier();

    for (int t = 0; t < NT; ++t) {
        const int cur = t & 1;
        const char* Ab = (const char*)&As[cur][0];
        const char* Bb = (const char*)&Bs[cur][0];
        bf16x8 afl[4][2], afh[4][2], bf[4][2];

        // ================= phase 1 =================
        #pragma unroll
        for (int i = 0; i < 4; ++i)
            #pragma unroll
            for (int kk = 0; kk < 2; ++kk)
                afl[i][kk] = *(const bf16x8*)(Ab + (wr*128 + i*16 + l16)*128
                              + ((((kk<<2)|quad) ^ swz) << 4));
        #pragma unroll
        for (int j = 0; j < 2; ++j)
            #pragma unroll
            for (int kk = 0; kk < 2; ++kk)
                bf[j][kk] = *(const bf16x8*)(Bb + (wc*64 + j*16 + l16)*128
                              + ((((kk<<2)|quad) ^ swz) << 4));
        if (t + 1 < NT)
            stage_half(A, m0, (t+1)*64, K, &As[cur^1][0], tid);
        __builtin_amdgcn_s_barrier();
        asm volatile("s_waitcnt lgkmcnt(0)" ::: "memory");
        __builtin_amdgcn_s_setprio(1);
        #pragma unroll
        for (int i = 0; i < 4; ++i)
            #pragma unroll
            for (int j = 0; j < 2; ++j) {
                acc[i][j] = MFMA16(afl[i][0], bf[j][0], acc[i][j]);
                acc[i][j] = MFMA16(afl[i][1], bf[j][1], acc[i][j]);
            }
        __builtin_amdgcn_s_setprio(0);
        __builtin_amdgcn_s_barrier();

        // ================= phase 2 =================
        #pragma unroll
        for (int j = 2; j < 4; ++j)
            #pragma unroll
            for (int kk = 0; kk < 2; ++kk)
                bf[j][kk] = *(const bf16x8*)(Bb + (wc*64 + j*16 + l16)*128
                              + ((((kk<<2)|quad) ^ swz) << 4));
        if (t + 1 < NT)
            stage_half(A, m0 + 128, (t+1)*64, K, &As[cur^1][8192], tid);
        __builtin_amdgcn_s_barrier();
        asm volatile("s_waitcnt lgkmcnt(0)" ::: "memory");
        __builtin_amdgcn_s_setprio(1);
        #pragma unroll
        for (int i = 0; i < 4; ++i)
            #pragma unroll
            for (int j = 2; j < 4; ++j) {
                acc[i][j] = MFMA16(afl[i][0], bf[j][0], acc[i][j]);
                acc[i][j] = MFMA16(afl[i][1], bf[j][1], acc[i][j]);
            }
        __builtin_amdgcn_s_setprio(0);
        __builtin_amdgcn_s_barrier();

        // ================= phase 3 =================
        #pragma unroll
        for (int i = 0; i < 4; ++i)
            #pragma unroll
            for (int kk = 0; kk < 2; ++kk)
                afh[i][kk] = *(const bf16x8*)(Ab + (wr*128 + (4+i)*16 + l16)*128
                              + ((((kk<<2)|quad) ^ swz) << 4));
        if (t + 2 < NT)
            stage_half(Bt, n0, (t+2)*64, K, &Bs[cur][0], tid);
        __builtin_amdgcn_s_barrier();
        asm volatile("s_waitcnt lgkmcnt(0)" ::: "memory");
        __builtin_amdgcn_s_setprio(1);
        #pragma unroll
        for (int i = 0; i < 4; ++i)
            #pragma unroll
            for (int j = 0; j < 2; ++j) {
                acc[4+i][j] = MFMA16(afh[i][0], bf[j][0], acc[4+i][j]);
                acc[4+i][j] = MFMA16(afh[i][1], bf[j][1], acc[4+i][j]);
            }
        __builtin_amdgcn_s_setprio(0);
        __builtin_amdgcn_s_barrier();

        // ================= phase 4 =================
        if (t + 2 < NT)
            stage_half(Bt, n0 + 128, (t+2)*64, K, &Bs[cur][8192], tid);
        asm volatile("s_waitcnt vmcnt(4)" ::: "memory");  // (t+1) halves landed
        __builtin_amdgcn_s_barrier();
        __builtin_amdgcn_s_setprio(1);
        #pragma unroll
        for (int i = 0; i < 4; ++i)
            #pragma unroll
            for (int j = 2; j < 4; ++j) {
                acc[4+i][j] = MFMA16(afh[i][0], bf[j][0], acc[4+i][j]);
                acc[4+i][j] = MFMA16(afh[i][1], bf[j][1], acc[4+i][j]);
            }
        __builtin_amdgcn_s_setprio(0);
        __builtin_amdgcn_s_barrier();
    }

    // ---- epilogue: D row = quad*4+r, col = l16 (m89/m91 layout) ----
    #pragma unroll
    for (int i = 0; i < 8; ++i)
        #pragma unroll
        for (int j = 0; j < 4; ++j) {
            int col = n0 + wc * 64 + j * 16 + l16;
            float bs = bias[col];
            #pragma unroll
            for (int r = 0; r < 4; ++r) {
                int row = m0 + wr * 128 + i * 16 + quad * 4 + r;
                float v = acc[i][j][r] + bs;
                if (MODE == 0) {
                    int which = col >> 11, h = (col >> 7) & 15, d = col & 127;
                    int bb = row >> 11, s = row & 2047;
                    __hip_bfloat16* o = (__hip_bfloat16*)outp;
                    size_t idx;
                    if (which == 2)   // V transposed: [BH][Dh][S]
                        idx = 2 * (size_t)BH * SEQ * DH +
                              ((size_t)(bb * NH + h) * DH + d) * SEQ + s;
                    else
                        idx = (size_t)which * BH * SEQ * DH +
                              ((size_t)(bb * NH + h) * SEQ + s) * DH + d;
                    o[idx] = __float2bfloat16(v);
                } else {
                    ((float*)outp)[(size_t)row * DM + col] = v;
                }
            }
        }
}

// ---------------------------------------------------------------------------
// Causal flash attention, 8-wave / 128 q-rows per block.
// Q,K bf16 [BH][S][Dh]; V bf16 [BH][Dh][S] (pre-transposed).
// 512 threads, 8 waves x 16 q rows, KVBLK=64.
// LDS = Ks 16KB + Vs 16KB = 32 KB; Ps (128x64, chunk-XOR-swizzled) ALIASES
// Ks (dead after QK^T); one extra barrier guards the overwrite.
// NO min-occupancy launch bound: round 5 proved forcing 8 waves/EU squeezes
// the unified VGPR/AGPR budget to 32 arch VGPRs -> accumulator spill ->
// 1.3 GB scratch traffic, 3x slower.  Let the allocator pick (~64);
// pe values are written IN PLACE over sacc so no extra array is live
// across the alias barrier.
// XCD-aware remap: each XCD owns 8 heads -> K/V working set L2-resident.
// Defer-max (T13, THR=8) skips the O-rescale on most tiles.
// ---------------------------------------------------------------------------
__global__ __launch_bounds__(512)
void attn_kernel(const __hip_bfloat16* __restrict__ q,
                 const __hip_bfloat16* __restrict__ k,
                 const __hip_bfloat16* __restrict__ v,
                 __hip_bfloat16* __restrict__ o)
{
    __shared__ __hip_bfloat16 Ks[4 * 64 * 32];    // 16 KB: [kk][64][32]; P alias
    __shared__ __hip_bfloat16 Vs[2 * 128 * 32];   // 16 KB: [f2][128][32]

    const int tid  = threadIdx.x;
    const int wave = tid >> 6, lane = tid & 63;
    const int quad = lane >> 4, l16 = lane & 15;

    // XCD-aware remap (bijective, 1024 blocks = 8 XCD x 8 bh x 16 qtiles):
    // HW assigns XCD = bid % 8; give each XCD a contiguous bh range so its
    // K/V working set (1-2 MB) stays L2-resident.  Heavy q-tiles first.
    const int bid = blockIdx.y * gridDim.x + blockIdx.x;
    const int xcd = bid & 7, j = bid >> 3;        // j in 0..127
    const int bh  = xcd * 8 + (j >> 4);
    const int qt  = 15 - (j & 15);
    const int q0 = qt * 128;
    const int nkt = 2 * qt + 2;                   // k-tiles covering q0+127
    const size_t base = (size_t)bh * SEQ * DH;    // same elem count for V^T
    const float scale = 0.08838834764831845f;     // 1/sqrt(128)

    // Q fragments in registers, prescaled: A[m=l16][k=quad*8+j]
    bf16x8 qf[4];
    #pragma unroll
    for (int kk = 0; kk < 4; ++kk) {
        bf16x8 raw = *(const bf16x8*)(
            q + base + (size_t)(q0 + wave * 16 + l16) * DH + kk * 32 + quad * 8);
        #pragma unroll
        for (int jj = 0; jj < 8; ++jj) {
            __hip_bfloat16 h = ((const __hip_bfloat16*)&raw)[jj];
            ((__hip_bfloat16*)&qf[kk])[jj] =
                __float2bfloat16(__bfloat162float(h) * scale);
        }
    }

    float m_run[4], l_run[4];
    f32x4 oacc[8] = {};
    #pragma unroll
    for (int r = 0; r < 4; ++r) { m_run[r] = -1e30f; l_run[r] = 0.f; }

    const int wmax = q0 + wave * 16 + 15;         // last unmasked row of wave

    for (int kt = 0; kt < nkt; ++kt) {
        __syncthreads();   // prior iter's Ks(P)/Vs reads done
        // ---- DMA-stage K tile (4 slabs [64][32]) and V^T tile (2 slabs) ----
        {
            const __hip_bfloat16* kbase = k + base + (size_t)(kt * 64) * DH;
            const __hip_bfloat16* vbase = v + base + kt * 64;
            #pragma unroll
            for (int p = 0; p < 2; ++p) {
                int c = p * 512 + tid;                 // chunk id = LDS/16B
                int kk = c >> 8, krow = (c >> 2) & 63, h = c & 3;
                const __hip_bfloat16* gk =
                    kbase + (size_t)krow * DH + kk * 32 + h * 8;
                __hip_bfloat16* lk = Ks + (size_t)(p * 512 + (tid & ~63)) * 8;
                __builtin_amdgcn_global_load_lds((g_u32*)gk, (lds_u32*)lk, 16, 0, 0);
                int f2 = c >> 9, d = (c >> 2) & 127;
                const __hip_bfloat16* gv =
                    vbase + (size_t)d * SEQ + f2 * 32 + h * 8;
                __hip_bfloat16* lv = Vs + (size_t)(p * 512 + (tid & ~63)) * 8;
                __builtin_amdgcn_global_load_lds((g_u32*)gv, (lds_u32*)lv, 16, 0, 0);
            }
        }
        __syncthreads();   // staging visible (vmcnt drain + barrier)

        const bool active = (kt * 64 <= wmax);
        f32x4 sacc[4];     // scores, then (in place) the exp'd P values

        if (active) {
            // ---- S = (Q*scale) K^T : 16 q rows x 64 k cols per wave ----
            #pragma unroll
            for (int f = 0; f < 4; ++f) sacc[f] = f32x4{0.f, 0.f, 0.f, 0.f};
            __builtin_amdgcn_s_setprio(1);
            #pragma unroll
            for (int kk = 0; kk < 4; ++kk)
                #pragma unroll
                for (int f = 0; f < 4; ++f) {
                    bf16x8 b = *(const bf16x8*)(
                        &Ks[kk * 2048 + (f * 16 + l16) * 32 + quad * 8]);
                    sacc[f] = MFMA16(qf[kk], b, sacc[f]);
                }
            __builtin_amdgcn_s_setprio(0);

            // ---- causal mask (diagonal tiles only) + online softmax ----
            const int qrow = q0 + wave * 16 + quad * 4;
            if (kt * 64 + 63 > q0 + wave * 16) {
                #pragma unroll
                for (int f = 0; f < 4; ++f)
                    #pragma unroll
                    for (int r = 0; r < 4; ++r) {
                        int kg = kt * 64 + f * 16 + l16;
                        if (kg > qrow + r) sacc[f][r] = -1e30f;
                    }
            }
            float mloc[4] = {-1e30f, -1e30f, -1e30f, -1e30f};
            #pragma unroll
            for (int f = 0; f < 4; ++f)
                #pragma unroll
                for (int r = 0; r < 4; ++r)
                    mloc[r] = fmaxf(mloc[r], sacc[f][r]);
            #pragma unroll
            for (int off = 1; off < 16; off <<= 1)
                #pragma unroll
                for (int r = 0; r < 4; ++r)
                    mloc[r] = fmaxf(mloc[r], __shfl_xor(mloc[r], off, 64));

            // ---- defer-max (T13): rescale only when max grew > THR ----
            bool ok = true;
            #pragma unroll
            for (int r = 0; r < 4; ++r) ok &= (mloc[r] <= m_run[r] + 8.f);
            if (!__all(ok)) {
                float alpha[4];
                #pragma unroll
                for (int r = 0; r < 4; ++r) {
                    float mn = fmaxf(m_run[r], mloc[r]);
                    alpha[r] = __expf(m_run[r] - mn);
                    m_run[r] = mn;
                    l_run[r] *= alpha[r];
                }
                #pragma unroll
                for (int dt = 0; dt < 8; ++dt)
                    #pragma unroll
                    for (int r = 0; r < 4; ++r) oacc[dt][r] *= alpha[r];
            }

            float lloc[4] = {0.f, 0.f, 0.f, 0.f};
            #pragma unroll
            for (int f = 0; f < 4; ++f)
                #pragma unroll
                for (int r = 0; r < 4; ++r) {
                    float pe = __expf(sacc[f][r] - m_run[r]);
                    sacc[f][r] = pe;              // in place: sacc now holds P
                    lloc[r] += pe;
                }
            #pragma unroll
            for (int off = 1; off < 16; off <<= 1)
                #pragma unroll
                for (int r = 0; r < 4; ++r)
                    lloc[r] += __shfl_xor(lloc[r], off, 64);
            #pragma unroll
            for (int r = 0; r < 4; ++r) l_run[r] += lloc[r];
        }

        __syncthreads();   // ALL waves' QK^T reads of Ks done before P alias

        if (active) {
            // ---- P (C-layout) -> swizzled alias region (wave-private rows):
            //      elem = row*64 + (chunk ^ (row&7))*8 + (l16&7),
            //      chunk = f*2 + (l16>>3) ----
            #pragma unroll
            for (int f = 0; f < 4; ++f)
                #pragma unroll
                for (int r = 0; r < 4; ++r) {
                    int row = wave * 16 + quad * 4 + r;
                    int ch  = (f * 2 + (l16 >> 3)) ^ (row & 7);
                    Ks[row * 64 + ch * 8 + (l16 & 7)] =
                        __float2bfloat16(sacc[f][r]);
                }
            // same-wave RAW covered by lgkmcnt; Ps rows are wave-private

            // ---- O += P V ----
            __builtin_amdgcn_s_setprio(1);
            #pragma unroll
            for (int f2 = 0; f2 < 2; ++f2) {
                int prow = wave * 16 + l16;
                bf16x8 a = *(const bf16x8*)(
                    &Ks[prow * 64 + (((f2 << 2) | quad) ^ (l16 & 7)) * 8]);
                #pragma unroll
                for (int dt = 0; dt < 8; ++dt) {
                    bf16x8 b = *(const bf16x8*)(
                        &Vs[f2 * 4096 + (dt * 16 + l16) * 32 + quad * 8]);
                    oacc[dt] = MFMA16(a, b, oacc[dt]);
                }
            }
            __builtin_amdgcn_s_setprio(0);
        }
    }

    // epilogue: normalize and store O (bf16) into [B][S][D_MODEL]
    const int bb = bh >> 4, h = bh & 15;
    #pragma unroll
    for (int dt = 0; dt < 8; ++dt)
        #pragma unroll
        for (int r = 0; r < 4; ++r) {
            int srow = q0 + wave * 16 + quad * 4 + r;
            float val = oacc[dt][r] / l_run[r];
            o[((size_t)(bb * SEQ + srow)) * DM + h * DH + dt * 16 + l16] =
                __float2bfloat16(val);
        }
}

// ---------------------------------------------------------------------------
extern "C" void kernel_launch(void* const* d_in, const int* in_sizes, int n_in,
                              void* d_out, int out_size, void* d_ws, size_t ws_size,
                              hipStream_t stream)
{
    const float* x     = (const float*)d_in[0];   // [4,2048,2048] fp32
    const float* w_qkv = (const float*)d_in[1];   // [2048,6144]   fp32
    const float* b_qkv = (const float*)d_in[2];   // [6144]        fp32
    const float* w_out = (const float*)d_in[3];   // [2048,2048]   fp32
    const float* b_out = (const float*)d_in[4];   // [2048]        fp32
    float* out = (float*)d_out;                   // [4,2048,2048] fp32
    __hip_bfloat16* ws = (__hip_bfloat16*)d_ws;

    constexpr size_t NX    = (size_t)MROWS * DM;        // 16.78M
    constexpr size_t NWQKV = (size_t)DM * 3 * DM;       // 12.58M
    constexpr size_t NWOUT = (size_t)DM * DM;           //  4.19M
    constexpr size_t T     = (size_t)BH * SEQ * DH;     // 16.78M

    __hip_bfloat16* xb    = ws;                         // reused as op later
    __hip_bfloat16* wqkvT = ws + NX;
    __hip_bfloat16* woutT = ws + NX + NWQKV;
    __hip_bfloat16* qkv   = ws + NX + NWQKV + NWOUT;    // q | k | v^T
    __hip_bfloat16* op    = xb;                         // [B][S][D] bf16

    // 0) precision/layout prep (memory-bound, ~35 us total)
    cvt_bf16<<<NX / (8 * 256), 256, 0, stream>>>(x, xb);
    cvt_T<<<dim3(3 * DM / 32, DM / 32), 256, 0, stream>>>(w_qkv, wqkvT, DM, 3 * DM);
    cvt_T<<<dim3(DM / 32, DM / 32), 256, 0, stream>>>(w_out, woutT, DM, DM);

    // 1) fused QKV projection -> q,k [BH][S][Dh], v [BH][Dh][S]
    gemm_bt256<0><<<dim3(3 * DM / 256, MROWS / 256), 512, 0, stream>>>(
        xb, wqkvT, b_qkv, qkv, DM);
    // 2) causal flash attention (128 q-rows / block, 8 waves, XCD-grouped)
    attn_kernel<<<dim3(SEQ / 128, BH), 512, 0, stream>>>(
        qkv, qkv + T, qkv + 2 * T, op);
    // 3) output projection -> fp32 d_out
    gemm_bt256<1><<<dim3(DM / 256, MROWS / 256), 512, 0, stream>>>(
        op, woutT, b_out, out, DM);
}

// Round 7
// 637.887 us; speedup vs baseline: 2.1089x; 1.0623x over previous
//
#include <hip/hip_runtime.h>
#include <hip/hip_bf16.h>

typedef short bf16x8 __attribute__((ext_vector_type(8)));   // 8 bf16 in 4 VGPRs
typedef float f32x4  __attribute__((ext_vector_type(4)));   // MFMA C/D frag

#define MFMA16(a,b,c) __builtin_amdgcn_mfma_f32_16x16x32_bf16((a),(b),(c),0,0,0)

typedef __attribute__((address_space(3))) unsigned int       lds_u32;
typedef const __attribute__((address_space(1))) unsigned int g_u32;

static constexpr int SEQ = 2048;
static constexpr int DM  = 2048;
static constexpr int NH  = 16;
static constexpr int DH  = 128;
static constexpr int BAT = 4;
static constexpr int BH  = BAT * NH;      // 64
static constexpr int MROWS = BAT * SEQ;   // 8192

// ---------------------------------------------------------------------------
// fp32 -> bf16 elementwise (8 elems/thread, 16B loads, 16B stores)
// ---------------------------------------------------------------------------
__global__ __launch_bounds__(256)
void cvt_bf16(const float* __restrict__ in, __hip_bfloat16* __restrict__ out)
{
    int i = blockIdx.x * 256 + threadIdx.x;
    const float4* p = (const float4*)in + (size_t)i * 2;
    float4 a = p[0], b = p[1];
    __hip_bfloat16 t[8];
    t[0]=__float2bfloat16(a.x); t[1]=__float2bfloat16(a.y);
    t[2]=__float2bfloat16(a.z); t[3]=__float2bfloat16(a.w);
    t[4]=__float2bfloat16(b.x); t[5]=__float2bfloat16(b.y);
    t[6]=__float2bfloat16(b.z); t[7]=__float2bfloat16(b.w);
    *(uint4*)(out + (size_t)i * 8) = *(uint4*)t;
}

// ---------------------------------------------------------------------------
// fp32 [K][N] -> bf16 [N][K] transpose-convert, 32x32 LDS tiles
// ---------------------------------------------------------------------------
__global__ __launch_bounds__(256)
void cvt_T(const float* __restrict__ in, __hip_bfloat16* __restrict__ out,
           int K, int N)
{
    __shared__ float t[32][33];
    const int n0 = blockIdx.x * 32, k0 = blockIdx.y * 32;
    const int r = threadIdx.x >> 3, c4 = (threadIdx.x & 7) * 4;
    float4 v = *(const float4*)(in + (size_t)(k0 + r) * N + n0 + c4);
    t[r][c4] = v.x; t[r][c4+1] = v.y; t[r][c4+2] = v.z; t[r][c4+3] = v.w;
    __syncthreads();
    __hip_bfloat16 o[4];
    #pragma unroll
    for (int j = 0; j < 4; ++j) o[j] = __float2bfloat16(t[c4 + j][r]);
    *(uint2*)(out + (size_t)(n0 + r) * K + k0 + c4) = *(uint2*)o;
}

// ---------------------------------------------------------------------------
// Stage one half-tile (128 rows x 64 k, bf16) into LDS via global_load_lds.
// LDS dest is LINEAR; XOR-swizzle (chunk' = k8 ^ (row&7)) applied by
// pre-swizzling the per-lane GLOBAL source address (rule #21).
// ---------------------------------------------------------------------------
__device__ __forceinline__
void stage_half(const __hip_bfloat16* __restrict__ g, int row0, int k0, int K,
                __hip_bfloat16* l, int tid)
{
    #pragma unroll
    for (int pass = 0; pass < 2; ++pass) {
        int c   = pass * 512 + tid;              // chunk index within half
        int row = c >> 3;                        // 0..127
        int k8  = (c & 7) ^ (row & 7);           // inverse-swizzled k-octet
        const __hip_bfloat16* gp = g + (size_t)(row0 + row) * K + k0 + k8 * 8;
        __hip_bfloat16* lp = l + (size_t)(pass * 512 + (tid & ~63)) * 8;
        __builtin_amdgcn_global_load_lds((g_u32*)gp, (lds_u32*)lp, 16, 0, 0);
    }
}

// ---------------------------------------------------------------------------
// 256x256-tile 8-phase GEMM (T1+T2+T3+T4+T5), BK=64, 8 waves (2M x 4N),
// 512 threads, 128 KiB LDS (2 tile dbuf x (A,B) x [256][64] bf16, XOR-swz).
// Block order (r7): XCD-chunked with m-fast half-stripes of height 2 so the
// A stripe (2MB) + current B panel (1MB) fit the 4MB XCD L2; round-6
// row-major chunks refetched B every m-row (FETCH 393MB vs 56MB unique).
// ---------------------------------------------------------------------------
template<int MODE>
__global__ __launch_bounds__(512)
void gemm_bt256(const __hip_bfloat16* __restrict__ A,
                const __hip_bfloat16* __restrict__ Bt,
                const float* __restrict__ bias,
                void* __restrict__ outp, int K)
{
    __shared__ __hip_bfloat16 As[2][16384];   // [buf][row*8 + k8] chunks
    __shared__ __hip_bfloat16 Bs[2][16384];

    const int tid  = threadIdx.x;
    const int wave = tid >> 6, lane = tid & 63;
    const int quad = lane >> 4, l16 = lane & 15;
    const int wr = wave >> 2, wc = wave & 3;   // 2 x 4 wave grid

    // XCD-chunked order: xcd owns m-rows [xcd*mpx, (xcd+1)*mpx); within the
    // chunk, half-stripes of 2 m-rows, m fast, n slow (bijective).
    const int bid  = blockIdx.y * gridDim.x + blockIdx.x;
    const int xcd  = bid & 7, local = bid >> 3;
    const int mpx  = gridDim.y >> 3;           // 4 for both call sites
    const int sub  = local / (gridDim.x * 2);
    const int rem  = local % (gridDim.x * 2);
    const int n0   = (rem >> 1) * 256;
    const int m0   = (xcd * mpx + sub * 2 + (rem & 1)) * 256;

    const int NT = K >> 6;                     // 64-wide K tiles
    const int swz = l16 & 7;                   // per-lane read-side XOR

    f32x4 acc[8][4] = {};

    stage_half(A,  m0,        0,  K, &As[0][0],    tid);
    stage_half(A,  m0 + 128,  0,  K, &As[0][8192], tid);
    stage_half(Bt, n0,        0,  K, &Bs[0][0],    tid);
    stage_half(Bt, n0 + 128,  0,  K, &Bs[0][8192], tid);
    stage_half(Bt, n0,        64, K, &Bs[1][0],    tid);
    stage_half(Bt, n0 + 128,  64, K, &Bs[1][8192], tid);
    asm volatile("s_waitcnt vmcnt(4)" ::: "memory");
    __builtin_amdgcn_s_barrier();

    for (int t = 0; t < NT; ++t) {
        const int cur = t & 1;
        const char* Ab = (const char*)&As[cur][0];
        const char* Bb = (const char*)&Bs[cur][0];
        bf16x8 afl[4][2], afh[4][2], bf[4][2];

        // ================= phase 1 =================
        #pragma unroll
        for (int i = 0; i < 4; ++i)
            #pragma unroll
            for (int kk = 0; kk < 2; ++kk)
                afl[i][kk] = *(const bf16x8*)(Ab + (wr*128 + i*16 + l16)*128
                              + ((((kk<<2)|quad) ^ swz) << 4));
        #pragma unroll
        for (int j = 0; j < 2; ++j)
            #pragma unroll
            for (int kk = 0; kk < 2; ++kk)
                bf[j][kk] = *(const bf16x8*)(Bb + (wc*64 + j*16 + l16)*128
                              + ((((kk<<2)|quad) ^ swz) << 4));
        if (t + 1 < NT)
            stage_half(A, m0, (t+1)*64, K, &As[cur^1][0], tid);
        __builtin_amdgcn_s_barrier();
        asm volatile("s_waitcnt lgkmcnt(0)" ::: "memory");
        __builtin_amdgcn_s_setprio(1);
        #pragma unroll
        for (int i = 0; i < 4; ++i)
            #pragma unroll
            for (int j = 0; j < 2; ++j) {
                acc[i][j] = MFMA16(afl[i][0], bf[j][0], acc[i][j]);
                acc[i][j] = MFMA16(afl[i][1], bf[j][1], acc[i][j]);
            }
        __builtin_amdgcn_s_setprio(0);
        __builtin_amdgcn_s_barrier();

        // ================= phase 2 =================
        #pragma unroll
        for (int j = 2; j < 4; ++j)
            #pragma unroll
            for (int kk = 0; kk < 2; ++kk)
                bf[j][kk] = *(const bf16x8*)(Bb + (wc*64 + j*16 + l16)*128
                              + ((((kk<<2)|quad) ^ swz) << 4));
        if (t + 1 < NT)
            stage_half(A, m0 + 128, (t+1)*64, K, &As[cur^1][8192], tid);
        __builtin_amdgcn_s_barrier();
        asm volatile("s_waitcnt lgkmcnt(0)" ::: "memory");
        __builtin_amdgcn_s_setprio(1);
        #pragma unroll
        for (int i = 0; i < 4; ++i)
            #pragma unroll
            for (int j = 2; j < 4; ++j) {
                acc[i][j] = MFMA16(afl[i][0], bf[j][0], acc[i][j]);
                acc[i][j] = MFMA16(afl[i][1], bf[j][1], acc[i][j]);
            }
        __builtin_amdgcn_s_setprio(0);
        __builtin_amdgcn_s_barrier();

        // ================= phase 3 =================
        #pragma unroll
        for (int i = 0; i < 4; ++i)
            #pragma unroll
            for (int kk = 0; kk < 2; ++kk)
                afh[i][kk] = *(const bf16x8*)(Ab + (wr*128 + (4+i)*16 + l16)*128
                              + ((((kk<<2)|quad) ^ swz) << 4));
        if (t + 2 < NT)
            stage_half(Bt, n0, (t+2)*64, K, &Bs[cur][0], tid);
        __builtin_amdgcn_s_barrier();
        asm volatile("s_waitcnt lgkmcnt(0)" ::: "memory");
        __builtin_amdgcn_s_setprio(1);
        #pragma unroll
        for (int i = 0; i < 4; ++i)
            #pragma unroll
            for (int j = 0; j < 2; ++j) {
                acc[4+i][j] = MFMA16(afh[i][0], bf[j][0], acc[4+i][j]);
                acc[4+i][j] = MFMA16(afh[i][1], bf[j][1], acc[4+i][j]);
            }
        __builtin_amdgcn_s_setprio(0);
        __builtin_amdgcn_s_barrier();

        // ================= phase 4 =================
        if (t + 2 < NT)
            stage_half(Bt, n0 + 128, (t+2)*64, K, &Bs[cur][8192], tid);
        asm volatile("s_waitcnt vmcnt(4)" ::: "memory");  // (t+1) halves landed
        __builtin_amdgcn_s_barrier();
        __builtin_amdgcn_s_setprio(1);
        #pragma unroll
        for (int i = 0; i < 4; ++i)
            #pragma unroll
            for (int j = 2; j < 4; ++j) {
                acc[4+i][j] = MFMA16(afh[i][0], bf[j][0], acc[4+i][j]);
                acc[4+i][j] = MFMA16(afh[i][1], bf[j][1], acc[4+i][j]);
            }
        __builtin_amdgcn_s_setprio(0);
        __builtin_amdgcn_s_barrier();
    }

    // ---- epilogue: D row = quad*4+r, col = l16 (m89/m91 layout) ----
    #pragma unroll
    for (int i = 0; i < 8; ++i)
        #pragma unroll
        for (int j = 0; j < 4; ++j) {
            int col = n0 + wc * 64 + j * 16 + l16;
            float bs = bias[col];
            #pragma unroll
            for (int r = 0; r < 4; ++r) {
                int row = m0 + wr * 128 + i * 16 + quad * 4 + r;
                float v = acc[i][j][r] + bs;
                if (MODE == 0) {
                    int which = col >> 11, h = (col >> 7) & 15, d = col & 127;
                    int bb = row >> 11, s = row & 2047;
                    __hip_bfloat16* o = (__hip_bfloat16*)outp;
                    size_t idx;
                    if (which == 2)   // V transposed: [BH][Dh][S]
                        idx = 2 * (size_t)BH * SEQ * DH +
                              ((size_t)(bb * NH + h) * DH + d) * SEQ + s;
                    else
                        idx = (size_t)which * BH * SEQ * DH +
                              ((size_t)(bb * NH + h) * SEQ + s) * DH + d;
                    o[idx] = __float2bfloat16(v);
                } else {
                    ((float*)outp)[(size_t)row * DM + col] = v;
                }
            }
        }
}

// ---------------------------------------------------------------------------
// Causal flash attention, 8-wave / 128 q-rows, TWO complementary q-tiles
// per block (qt, 15-qt) processed sequentially -> every block does exactly
// 2*15+4 = 34 k-tile iterations (round-6's remap gave each CU four SAME-qt
// blocks: 16x finish-time spread, 26% occupancy).  Grid 512 = 64 bh x 8
// pairs, 2 blocks/CU, uniformly busy.
// Q,K bf16 [BH][S][Dh]; V bf16 [BH][Dh][S] (pre-transposed).
// LDS = Ks 16KB + Vs 16KB + Ps 18KB (own region, stride 72 — R4-proven)
// = 50KB -> no P/K alias barrier: 2 barriers/iter.
// XCD remap keeps each XCD on 8 heads (K/V L2-resident, FETCH 49MB in r6).
// Defer-max (T13, THR=8).  No min-occupancy bound (r5 spill lesson).
// ---------------------------------------------------------------------------
__global__ __launch_bounds__(512)
void attn_kernel(const __hip_bfloat16* __restrict__ q,
                 const __hip_bfloat16* __restrict__ k,
                 const __hip_bfloat16* __restrict__ v,
                 __hip_bfloat16* __restrict__ o)
{
    __shared__ __hip_bfloat16 Ks[4 * 64 * 32];    // 16 KB: [kk][64][32]
    __shared__ __hip_bfloat16 Vs[2 * 128 * 32];   // 16 KB: [f2][128][32]
    __shared__ __hip_bfloat16 Ps[128 * 72];       // 18 KB: [qrow][72]

    const int tid  = threadIdx.x;
    const int wave = tid >> 6, lane = tid & 63;
    const int quad = lane >> 4, l16 = lane & 15;

    // grid = dim3(8, 64) -> 512 blocks; xcd = bid&7 owns bh in [xcd*8,xcd*8+8)
    const int bid = blockIdx.y * gridDim.x + blockIdx.x;
    const int xcd = bid & 7, idx = bid >> 3;      // idx in [0,64)
    const int bh  = xcd * 8 + (idx >> 3);
    const int pr  = idx & 7;                      // pair index
    const size_t base = (size_t)bh * SEQ * DH;    // same elem count for V^T
    const float scale = 0.08838834764831845f;     // 1/sqrt(128)
    const int bb = bh >> 4, hh = bh & 15;

    for (int half = 0; half < 2; ++half) {
        const int qt  = half ? (15 - pr) : pr;
        const int q0  = qt * 128;
        const int nkt = 2 * qt + 2;               // k-tiles covering q0+127

        // Q fragments in registers, prescaled: A[m=l16][k=quad*8+j]
        bf16x8 qf[4];
        #pragma unroll
        for (int kk = 0; kk < 4; ++kk) {
            bf16x8 raw = *(const bf16x8*)(
                q + base + (size_t)(q0 + wave * 16 + l16) * DH + kk * 32 + quad * 8);
            #pragma unroll
            for (int jj = 0; jj < 8; ++jj) {
                __hip_bfloat16 h = ((const __hip_bfloat16*)&raw)[jj];
                ((__hip_bfloat16*)&qf[kk])[jj] =
                    __float2bfloat16(__bfloat162float(h) * scale);
            }
        }

        float m_run[4], l_run[4];
        f32x4 oacc[8] = {};
        #pragma unroll
        for (int r = 0; r < 4; ++r) { m_run[r] = -1e30f; l_run[r] = 0.f; }

        const int wmax = q0 + wave * 16 + 15;     // last unmasked row of wave

        for (int kt = 0; kt < nkt; ++kt) {
            __syncthreads();   // prior iter's (or prior half's) Ks/Vs reads done
            // ---- DMA-stage K tile (4 slabs [64][32]) + V^T tile (2 slabs) ----
            {
                const __hip_bfloat16* kbase = k + base + (size_t)(kt * 64) * DH;
                const __hip_bfloat16* vbase = v + base + kt * 64;
                #pragma unroll
                for (int p = 0; p < 2; ++p) {
                    int c = p * 512 + tid;             // chunk id = LDS/16B
                    int kk = c >> 8, krow = (c >> 2) & 63, h = c & 3;
                    const __hip_bfloat16* gk =
                        kbase + (size_t)krow * DH + kk * 32 + h * 8;
                    __hip_bfloat16* lk = Ks + (size_t)(p * 512 + (tid & ~63)) * 8;
                    __builtin_amdgcn_global_load_lds((g_u32*)gk, (lds_u32*)lk, 16, 0, 0);
                    int f2 = c >> 9, d = (c >> 2) & 127;
                    const __hip_bfloat16* gv =
                        vbase + (size_t)d * SEQ + f2 * 32 + h * 8;
                    __hip_bfloat16* lv = Vs + (size_t)(p * 512 + (tid & ~63)) * 8;
                    __builtin_amdgcn_global_load_lds((g_u32*)gv, (lds_u32*)lv, 16, 0, 0);
                }
            }
            __syncthreads();   // staging visible (vmcnt drain + barrier)

            if (kt * 64 > wmax) continue;   // wave fully masked for this tile

            // ---- S = (Q*scale) K^T : 16 q rows x 64 k cols per wave ----
            f32x4 sacc[4] = {};
            __builtin_amdgcn_s_setprio(1);
            #pragma unroll
            for (int kk = 0; kk < 4; ++kk)
                #pragma unroll
                for (int f = 0; f < 4; ++f) {
                    bf16x8 b = *(const bf16x8*)(
                        &Ks[kk * 2048 + (f * 16 + l16) * 32 + quad * 8]);
                    sacc[f] = MFMA16(qf[kk], b, sacc[f]);
                }
            __builtin_amdgcn_s_setprio(0);

            // ---- causal mask (diagonal tiles only) + online softmax ----
            const int qrow = q0 + wave * 16 + quad * 4;
            if (kt * 64 + 63 > q0 + wave * 16) {
                #pragma unroll
                for (int f = 0; f < 4; ++f)
                    #pragma unroll
                    for (int r = 0; r < 4; ++r) {
                        int kg = kt * 64 + f * 16 + l16;
                        if (kg > qrow + r) sacc[f][r] = -1e30f;
                    }
            }
            float mloc[4] = {-1e30f, -1e30f, -1e30f, -1e30f};
            #pragma unroll
            for (int f = 0; f < 4; ++f)
                #pragma unroll
                for (int r = 0; r < 4; ++r)
                    mloc[r] = fmaxf(mloc[r], sacc[f][r]);
            #pragma unroll
            for (int off = 1; off < 16; off <<= 1)
                #pragma unroll
                for (int r = 0; r < 4; ++r)
                    mloc[r] = fmaxf(mloc[r], __shfl_xor(mloc[r], off, 64));

            // ---- defer-max (T13): rescale only when max grew > THR ----
            bool ok = true;
            #pragma unroll
            for (int r = 0; r < 4; ++r) ok &= (mloc[r] <= m_run[r] + 8.f);
            if (!__all(ok)) {
                float alpha[4];
                #pragma unroll
                for (int r = 0; r < 4; ++r) {
                    float mn = fmaxf(m_run[r], mloc[r]);
                    alpha[r] = __expf(m_run[r] - mn);
                    m_run[r] = mn;
                    l_run[r] *= alpha[r];
                }
                #pragma unroll
                for (int dt = 0; dt < 8; ++dt)
                    #pragma unroll
                    for (int r = 0; r < 4; ++r) oacc[dt][r] *= alpha[r];
            }

            float lloc[4] = {0.f, 0.f, 0.f, 0.f};
            #pragma unroll
            for (int f = 0; f < 4; ++f)
                #pragma unroll
                for (int r = 0; r < 4; ++r) {
                    float pe = __expf(sacc[f][r] - m_run[r]);
                    sacc[f][r] = pe;              // in place: sacc now holds P
                    lloc[r] += pe;
                }
            #pragma unroll
            for (int off = 1; off < 16; off <<= 1)
                #pragma unroll
                for (int r = 0; r < 4; ++r)
                    lloc[r] += __shfl_xor(lloc[r], off, 64);
            #pragma unroll
            for (int r = 0; r < 4; ++r) l_run[r] += lloc[r];

            // ---- P (C-layout) -> own LDS rows (wave-private, stride 72) ----
            #pragma unroll
            for (int f = 0; f < 4; ++f)
                #pragma unroll
                for (int r = 0; r < 4; ++r)
                    Ps[(wave * 16 + quad * 4 + r) * 72 + f * 16 + l16] =
                        __float2bfloat16(sacc[f][r]);
            // same-wave RAW covered by lgkmcnt; Ps rows are wave-private

            // ---- O += P V ----
            __builtin_amdgcn_s_setprio(1);
            #pragma unroll
            for (int f2 = 0; f2 < 2; ++f2) {
                bf16x8 a = *(const bf16x8*)(
                    &Ps[(wave * 16 + l16) * 72 + f2 * 32 + quad * 8]);
                #pragma unroll
                for (int dt = 0; dt < 8; ++dt) {
                    bf16x8 b = *(const bf16x8*)(
                        &Vs[f2 * 4096 + (dt * 16 + l16) * 32 + quad * 8]);
                    oacc[dt] = MFMA16(a, b, oacc[dt]);
                }
            }
            __builtin_amdgcn_s_setprio(0);
        }

        // epilogue: normalize and store O (bf16) into [B][S][D_MODEL]
        #pragma unroll
        for (int dt = 0; dt < 8; ++dt)
            #pragma unroll
            for (int r = 0; r < 4; ++r) {
                int srow = q0 + wave * 16 + quad * 4 + r;
                float val = oacc[dt][r] / l_run[r];
                o[((size_t)(bb * SEQ + srow)) * DM + hh * DH + dt * 16 + l16] =
                    __float2bfloat16(val);
            }
        // next half's first top-of-loop __syncthreads guards Ks/Vs reuse
    }
}

// ---------------------------------------------------------------------------
extern "C" void kernel_launch(void* const* d_in, const int* in_sizes, int n_in,
                              void* d_out, int out_size, void* d_ws, size_t ws_size,
                              hipStream_t stream)
{
    const float* x     = (const float*)d_in[0];   // [4,2048,2048] fp32
    const float* w_qkv = (const float*)d_in[1];   // [2048,6144]   fp32
    const float* b_qkv = (const float*)d_in[2];   // [6144]        fp32
    const float* w_out = (const float*)d_in[3];   // [2048,2048]   fp32
    const float* b_out = (const float*)d_in[4];   // [2048]        fp32
    float* out = (float*)d_out;                   // [4,2048,2048] fp32
    __hip_bfloat16* ws = (__hip_bfloat16*)d_ws;

    constexpr size_t NX    = (size_t)MROWS * DM;        // 16.78M
    constexpr size_t NWQKV = (size_t)DM * 3 * DM;       // 12.58M
    constexpr size_t NWOUT = (size_t)DM * DM;           //  4.19M
    constexpr size_t T     = (size_t)BH * SEQ * DH;     // 16.78M

    __hip_bfloat16* xb    = ws;                         // reused as op later
    __hip_bfloat16* wqkvT = ws + NX;
    __hip_bfloat16* woutT = ws + NX + NWQKV;
    __hip_bfloat16* qkv   = ws + NX + NWQKV + NWOUT;    // q | k | v^T
    __hip_bfloat16* op    = xb;                         // [B][S][D] bf16

    // 0) precision/layout prep (memory-bound, ~35 us total)
    cvt_bf16<<<NX / (8 * 256), 256, 0, stream>>>(x, xb);
    cvt_T<<<dim3(3 * DM / 32, DM / 32), 256, 0, stream>>>(w_qkv, wqkvT, DM, 3 * DM);
    cvt_T<<<dim3(DM / 32, DM / 32), 256, 0, stream>>>(w_out, woutT, DM, DM);

    // 1) fused QKV projection -> q,k [BH][S][Dh], v [BH][Dh][S]
    gemm_bt256<0><<<dim3(3 * DM / 256, MROWS / 256), 512, 0, stream>>>(
        xb, wqkvT, b_qkv, qkv, DM);
    // 2) causal flash attention (paired q-tiles, 512 balanced blocks)
    attn_kernel<<<dim3(8, BH), 512, 0, stream>>>(
        qkv, qkv + T, qkv + 2 * T, op);
    // 3) output projection -> fp32 d_out
    gemm_bt256<1><<<dim3(DM / 256, MROWS / 256), 512, 0, stream>>>(
        op, woutT, b_out, out, DM);
}

// Round 8
// 621.443 us; speedup vs baseline: 2.1647x; 1.0265x over previous
//
#include <hip/hip_runtime.h>
#include <hip/hip_bf16.h>

typedef short bf16x8 __attribute__((ext_vector_type(8)));   // 8 bf16 in 4 VGPRs
typedef float f32x4  __attribute__((ext_vector_type(4)));   // MFMA C/D frag

#define MFMA16(a,b,c) __builtin_amdgcn_mfma_f32_16x16x32_bf16((a),(b),(c),0,0,0)

typedef __attribute__((address_space(3))) unsigned int       lds_u32;
typedef const __attribute__((address_space(1))) unsigned int g_u32;

static constexpr int SEQ = 2048;
static constexpr int DM  = 2048;
static constexpr int NH  = 16;
static constexpr int DH  = 128;
static constexpr int BAT = 4;
static constexpr int BH  = BAT * NH;      // 64
static constexpr int MROWS = BAT * SEQ;   // 8192

// ---------------------------------------------------------------------------
// fp32 -> bf16 elementwise (8 elems/thread, 16B loads, 16B stores)
// ---------------------------------------------------------------------------
__global__ __launch_bounds__(256)
void cvt_bf16(const float* __restrict__ in, __hip_bfloat16* __restrict__ out)
{
    int i = blockIdx.x * 256 + threadIdx.x;
    const float4* p = (const float4*)in + (size_t)i * 2;
    float4 a = p[0], b = p[1];
    __hip_bfloat16 t[8];
    t[0]=__float2bfloat16(a.x); t[1]=__float2bfloat16(a.y);
    t[2]=__float2bfloat16(a.z); t[3]=__float2bfloat16(a.w);
    t[4]=__float2bfloat16(b.x); t[5]=__float2bfloat16(b.y);
    t[6]=__float2bfloat16(b.z); t[7]=__float2bfloat16(b.w);
    *(uint4*)(out + (size_t)i * 8) = *(uint4*)t;
}

// ---------------------------------------------------------------------------
// fp32 [K][N] -> bf16 [N][K] transpose-convert, 32x32 LDS tiles
// ---------------------------------------------------------------------------
__global__ __launch_bounds__(256)
void cvt_T(const float* __restrict__ in, __hip_bfloat16* __restrict__ out,
           int K, int N)
{
    __shared__ float t[32][33];
    const int n0 = blockIdx.x * 32, k0 = blockIdx.y * 32;
    const int r = threadIdx.x >> 3, c4 = (threadIdx.x & 7) * 4;
    float4 v = *(const float4*)(in + (size_t)(k0 + r) * N + n0 + c4);
    t[r][c4] = v.x; t[r][c4+1] = v.y; t[r][c4+2] = v.z; t[r][c4+3] = v.w;
    __syncthreads();
    __hip_bfloat16 o[4];
    #pragma unroll
    for (int j = 0; j < 4; ++j) o[j] = __float2bfloat16(t[c4 + j][r]);
    *(uint2*)(out + (size_t)(n0 + r) * K + k0 + c4) = *(uint2*)o;
}

// ---------------------------------------------------------------------------
// Stage one half-tile (128 rows x 64 k, bf16) into LDS via global_load_lds.
// LDS dest is LINEAR; XOR-swizzle (chunk' = k8 ^ (row&7)) applied by
// pre-swizzling the per-lane GLOBAL source address (rule #21).
// ---------------------------------------------------------------------------
__device__ __forceinline__
void stage_half(const __hip_bfloat16* __restrict__ g, int row0, int k0, int K,
                __hip_bfloat16* l, int tid)
{
    #pragma unroll
    for (int pass = 0; pass < 2; ++pass) {
        int c   = pass * 512 + tid;              // chunk index within half
        int row = c >> 3;                        // 0..127
        int k8  = (c & 7) ^ (row & 7);           // inverse-swizzled k-octet
        const __hip_bfloat16* gp = g + (size_t)(row0 + row) * K + k0 + k8 * 8;
        __hip_bfloat16* lp = l + (size_t)(pass * 512 + (tid & ~63)) * 8;
        __builtin_amdgcn_global_load_lds((g_u32*)gp, (lds_u32*)lp, 16, 0, 0);
    }
}

// ---------------------------------------------------------------------------
// 256x256-tile 8-phase GEMM, BK=64, 8 waves (2M x 4N), 512 threads,
// 128 KiB LDS (2 tile dbuf x (A,B), XOR-swz).
// r8 schedule: deepen the prefetch pipeline to 3 half-tiles in flight
// (vmcnt(6), m201's magic number) by staging at the legality frontier:
//   ph1: ds afl+bf01; stage A1(t+1)          (A1 region dead since t-1 ph3)
//   ph2: ds bf23
//   ph3: ds afh;      stage B0(t+2)          (B0 region dead after ph2)
//   ph4: stage B1(t+2) + A0(t+2)             (A0 region dead after ph3!)
//        barrier; MFMA; vmcnt(6); barrier    (drain AFTER the MFMA cluster)
// Drain set at ph4 = {B1,A0,A1}(t+1): windows 4/4/3 phases (was 3/2) vs
// ~900cy HBM latency.  r7's vmcnt(4) drained A(t+1) only ~2 phases after
// issue -> ~250cy stall/tile -> MfmaUtil stuck at 36%.
// Block order: XCD-chunked, m-fast half-stripes of 2 (r7).
// ---------------------------------------------------------------------------
template<int MODE>
__global__ __launch_bounds__(512)
void gemm_bt256(const __hip_bfloat16* __restrict__ A,
                const __hip_bfloat16* __restrict__ Bt,
                const float* __restrict__ bias,
                void* __restrict__ outp, int K)
{
    __shared__ __hip_bfloat16 As[2][16384];   // [buf][row*8 + k8] chunks
    __shared__ __hip_bfloat16 Bs[2][16384];

    const int tid  = threadIdx.x;
    const int wave = tid >> 6, lane = tid & 63;
    const int quad = lane >> 4, l16 = lane & 15;
    const int wr = wave >> 2, wc = wave & 3;   // 2 x 4 wave grid

    const int bid  = blockIdx.y * gridDim.x + blockIdx.x;
    const int xcd  = bid & 7, local = bid >> 3;
    const int mpx  = gridDim.y >> 3;           // 4 for both call sites
    const int sub  = local / (gridDim.x * 2);
    const int rem  = local % (gridDim.x * 2);
    const int n0   = (rem >> 1) * 256;
    const int m0   = (xcd * mpx + sub * 2 + (rem & 1)) * 256;

    const int NT = K >> 6;                     // 64-wide K tiles
    const int swz = l16 & 7;                   // per-lane read-side XOR

    f32x4 acc[8][4] = {};

    // prologue: tile0 (4 halves) + B0,B1,A0 of tile1 -> 3 halves in flight
    stage_half(A,  m0,        0,  K, &As[0][0],    tid);
    stage_half(A,  m0 + 128,  0,  K, &As[0][8192], tid);
    stage_half(Bt, n0,        0,  K, &Bs[0][0],    tid);
    stage_half(Bt, n0 + 128,  0,  K, &Bs[0][8192], tid);
    stage_half(Bt, n0,        64, K, &Bs[1][0],    tid);
    stage_half(Bt, n0 + 128,  64, K, &Bs[1][8192], tid);
    stage_half(A,  m0,        64, K, &As[1][0],    tid);
    asm volatile("s_waitcnt vmcnt(6)" ::: "memory");
    __builtin_amdgcn_s_barrier();

    for (int t = 0; t < NT; ++t) {
        const int cur = t & 1;
        const char* Ab = (const char*)&As[cur][0];
        const char* Bb = (const char*)&Bs[cur][0];
        bf16x8 afl[4][2], afh[4][2], bf[4][2];

        // ================= phase 1: afl+bf01; stage A1(t+1) ===============
        #pragma unroll
        for (int i = 0; i < 4; ++i)
            #pragma unroll
            for (int kk = 0; kk < 2; ++kk)
                afl[i][kk] = *(const bf16x8*)(Ab + (wr*128 + i*16 + l16)*128
                              + ((((kk<<2)|quad) ^ swz) << 4));
        #pragma unroll
        for (int j = 0; j < 2; ++j)
            #pragma unroll
            for (int kk = 0; kk < 2; ++kk)
                bf[j][kk] = *(const bf16x8*)(Bb + (wc*64 + j*16 + l16)*128
                              + ((((kk<<2)|quad) ^ swz) << 4));
        if (t + 1 < NT)
            stage_half(A, m0 + 128, (t+1)*64, K, &As[(t+1)&1][8192], tid);
        __builtin_amdgcn_s_barrier();
        asm volatile("s_waitcnt lgkmcnt(0)" ::: "memory");
        __builtin_amdgcn_s_setprio(1);
        #pragma unroll
        for (int i = 0; i < 4; ++i)
            #pragma unroll
            for (int j = 0; j < 2; ++j) {
                acc[i][j] = MFMA16(afl[i][0], bf[j][0], acc[i][j]);
                acc[i][j] = MFMA16(afl[i][1], bf[j][1], acc[i][j]);
            }
        __builtin_amdgcn_s_setprio(0);
        __builtin_amdgcn_s_barrier();

        // ================= phase 2: bf23 ==================================
        #pragma unroll
        for (int j = 2; j < 4; ++j)
            #pragma unroll
            for (int kk = 0; kk < 2; ++kk)
                bf[j][kk] = *(const bf16x8*)(Bb + (wc*64 + j*16 + l16)*128
                              + ((((kk<<2)|quad) ^ swz) << 4));
        __builtin_amdgcn_s_barrier();
        asm volatile("s_waitcnt lgkmcnt(0)" ::: "memory");
        __builtin_amdgcn_s_setprio(1);
        #pragma unroll
        for (int i = 0; i < 4; ++i)
            #pragma unroll
            for (int j = 2; j < 4; ++j) {
                acc[i][j] = MFMA16(afl[i][0], bf[j][0], acc[i][j]);
                acc[i][j] = MFMA16(afl[i][1], bf[j][1], acc[i][j]);
            }
        __builtin_amdgcn_s_setprio(0);
        __builtin_amdgcn_s_barrier();

        // ================= phase 3: afh; stage B0(t+2) ====================
        #pragma unroll
        for (int i = 0; i < 4; ++i)
            #pragma unroll
            for (int kk = 0; kk < 2; ++kk)
                afh[i][kk] = *(const bf16x8*)(Ab + (wr*128 + (4+i)*16 + l16)*128
                              + ((((kk<<2)|quad) ^ swz) << 4));
        if (t + 2 < NT)
            stage_half(Bt, n0, (t+2)*64, K, &Bs[cur][0], tid);
        __builtin_amdgcn_s_barrier();
        asm volatile("s_waitcnt lgkmcnt(0)" ::: "memory");
        __builtin_amdgcn_s_setprio(1);
        #pragma unroll
        for (int i = 0; i < 4; ++i)
            #pragma unroll
            for (int j = 0; j < 2; ++j) {
                acc[4+i][j] = MFMA16(afh[i][0], bf[j][0], acc[4+i][j]);
                acc[4+i][j] = MFMA16(afh[i][1], bf[j][1], acc[4+i][j]);
            }
        __builtin_amdgcn_s_setprio(0);
        __builtin_amdgcn_s_barrier();

        // ======= phase 4: stage B1(t+2)+A0(t+2); MFMA; vmcnt(6) ===========
        if (t + 2 < NT) {
            stage_half(Bt, n0 + 128, (t+2)*64, K, &Bs[cur][8192], tid);
            stage_half(A,  m0,       (t+2)*64, K, &As[cur][0],    tid);
        }
        __builtin_amdgcn_s_barrier();
        __builtin_amdgcn_s_setprio(1);
        #pragma unroll
        for (int i = 0; i < 4; ++i)
            #pragma unroll
            for (int j = 2; j < 4; ++j) {
                acc[4+i][j] = MFMA16(afh[i][0], bf[j][0], acc[4+i][j]);
                acc[4+i][j] = MFMA16(afh[i][1], bf[j][1], acc[4+i][j]);
            }
        __builtin_amdgcn_s_setprio(0);
        if (t + 2 < NT)
            asm volatile("s_waitcnt vmcnt(6)" ::: "memory");
        else
            asm volatile("s_waitcnt vmcnt(0)" ::: "memory");
        __builtin_amdgcn_s_barrier();
    }

    // ---- epilogue: D row = quad*4+r, col = l16 (m89/m91 layout) ----
    #pragma unroll
    for (int i = 0; i < 8; ++i)
        #pragma unroll
        for (int j = 0; j < 4; ++j) {
            int col = n0 + wc * 64 + j * 16 + l16;
            float bs = bias[col];
            #pragma unroll
            for (int r = 0; r < 4; ++r) {
                int row = m0 + wr * 128 + i * 16 + quad * 4 + r;
                float v = acc[i][j][r] + bs;
                if (MODE == 0) {
                    int which = col >> 11, h = (col >> 7) & 15, d = col & 127;
                    int bb = row >> 11, s = row & 2047;
                    __hip_bfloat16* o = (__hip_bfloat16*)outp;
                    size_t idx;
                    if (which == 2)   // V transposed: [BH][Dh][S]
                        idx = 2 * (size_t)BH * SEQ * DH +
                              ((size_t)(bb * NH + h) * DH + d) * SEQ + s;
                    else
                        idx = (size_t)which * BH * SEQ * DH +
                              ((size_t)(bb * NH + h) * SEQ + s) * DH + d;
                    o[idx] = __float2bfloat16(v);
                } else {
                    ((float*)outp)[(size_t)row * DM + col] = v;
                }
            }
        }
}

// ---------------------------------------------------------------------------
// Causal flash attention, 8-wave / 128 q-rows, ONE q-tile per block,
// grid 1024 ordered by DESCENDING qt (qt = 15 - bid>>6): heavy blocks
// launch first, light blocks backfill the tail (r6's imbalance came from
// same-qt-per-CU residency, not from single-qt blocks per se).
// LDS = Ks 16KB + Vs 16KB + Ps 18KB = 50 KB -> 3 blocks/CU (150<=160KB),
// 24 waves/CU at VGPR<=64 (r7 measured exactly 64) vs r7's 2 blocks/CU.
// XCD remap keeps each XCD on 8 heads (K/V L2-resident).
// Defer-max (T13, THR=8).  No min-occupancy bound (r5 spill lesson).
// ---------------------------------------------------------------------------
__global__ __launch_bounds__(512)
void attn_kernel(const __hip_bfloat16* __restrict__ q,
                 const __hip_bfloat16* __restrict__ k,
                 const __hip_bfloat16* __restrict__ v,
                 __hip_bfloat16* __restrict__ o)
{
    __shared__ __hip_bfloat16 Ks[4 * 64 * 32];    // 16 KB: [kk][64][32]
    __shared__ __hip_bfloat16 Vs[2 * 128 * 32];   // 16 KB: [f2][128][32]
    __shared__ __hip_bfloat16 Ps[128 * 72];       // 18 KB: [qrow][72]

    const int tid  = threadIdx.x;
    const int wave = tid >> 6, lane = tid & 63;
    const int quad = lane >> 4, l16 = lane & 15;

    // grid = dim3(16, 64) -> bid in [0,1024); xcd = bid&7 owns 8 heads;
    // qt descends with bid so the work-heavy blocks dispatch first.
    const int bid = blockIdx.y * gridDim.x + blockIdx.x;
    const int bh  = (bid & 7) * 8 + ((bid >> 3) & 7);
    const int qt  = 15 - (bid >> 6);
    const int q0  = qt * 128;
    const int nkt = 2 * qt + 2;                   // k-tiles covering q0+127
    const size_t base = (size_t)bh * SEQ * DH;    // same elem count for V^T
    const float scale = 0.08838834764831845f;     // 1/sqrt(128)
    const int bb = bh >> 4, hh = bh & 15;

    // Q fragments in registers, prescaled: A[m=l16][k=quad*8+j]
    bf16x8 qf[4];
    #pragma unroll
    for (int kk = 0; kk < 4; ++kk) {
        bf16x8 raw = *(const bf16x8*)(
            q + base + (size_t)(q0 + wave * 16 + l16) * DH + kk * 32 + quad * 8);
        #pragma unroll
        for (int jj = 0; jj < 8; ++jj) {
            __hip_bfloat16 h = ((const __hip_bfloat16*)&raw)[jj];
            ((__hip_bfloat16*)&qf[kk])[jj] =
                __float2bfloat16(__bfloat162float(h) * scale);
        }
    }

    float m_run[4], l_run[4];
    f32x4 oacc[8] = {};
    #pragma unroll
    for (int r = 0; r < 4; ++r) { m_run[r] = -1e30f; l_run[r] = 0.f; }

    const int wmax = q0 + wave * 16 + 15;         // last unmasked row of wave

    for (int kt = 0; kt < nkt; ++kt) {
        __syncthreads();   // prior iter's Ks/Vs reads done
        // ---- DMA-stage K tile (4 slabs [64][32]) + V^T tile (2 slabs) ----
        {
            const __hip_bfloat16* kbase = k + base + (size_t)(kt * 64) * DH;
            const __hip_bfloat16* vbase = v + base + kt * 64;
            #pragma unroll
            for (int p = 0; p < 2; ++p) {
                int c = p * 512 + tid;             // chunk id = LDS/16B
                int kk = c >> 8, krow = (c >> 2) & 63, h = c & 3;
                const __hip_bfloat16* gk =
                    kbase + (size_t)krow * DH + kk * 32 + h * 8;
                __hip_bfloat16* lk = Ks + (size_t)(p * 512 + (tid & ~63)) * 8;
                __builtin_amdgcn_global_load_lds((g_u32*)gk, (lds_u32*)lk, 16, 0, 0);
                int f2 = c >> 9, d = (c >> 2) & 127;
                const __hip_bfloat16* gv =
                    vbase + (size_t)d * SEQ + f2 * 32 + h * 8;
                __hip_bfloat16* lv = Vs + (size_t)(p * 512 + (tid & ~63)) * 8;
                __builtin_amdgcn_global_load_lds((g_u32*)gv, (lds_u32*)lv, 16, 0, 0);
            }
        }
        __syncthreads();   // staging visible (vmcnt drain + barrier)

        if (kt * 64 > wmax) continue;   // wave fully masked for this tile

        // ---- S = (Q*scale) K^T : 16 q rows x 64 k cols per wave ----
        f32x4 sacc[4] = {};
        __builtin_amdgcn_s_setprio(1);
        #pragma unroll
        for (int kk = 0; kk < 4; ++kk)
            #pragma unroll
            for (int f = 0; f < 4; ++f) {
                bf16x8 b = *(const bf16x8*)(
                    &Ks[kk * 2048 + (f * 16 + l16) * 32 + quad * 8]);
                sacc[f] = MFMA16(qf[kk], b, sacc[f]);
            }
        __builtin_amdgcn_s_setprio(0);

        // ---- causal mask (diagonal tiles only) + online softmax ----
        const int qrow = q0 + wave * 16 + quad * 4;
        if (kt * 64 + 63 > q0 + wave * 16) {
            #pragma unroll
            for (int f = 0; f < 4; ++f)
                #pragma unroll
                for (int r = 0; r < 4; ++r) {
                    int kg = kt * 64 + f * 16 + l16;
                    if (kg > qrow + r) sacc[f][r] = -1e30f;
                }
        }
        float mloc[4] = {-1e30f, -1e30f, -1e30f, -1e30f};
        #pragma unroll
        for (int f = 0; f < 4; ++f)
            #pragma unroll
            for (int r = 0; r < 4; ++r)
                mloc[r] = fmaxf(mloc[r], sacc[f][r]);
        #pragma unroll
        for (int off = 1; off < 16; off <<= 1)
            #pragma unroll
            for (int r = 0; r < 4; ++r)
                mloc[r] = fmaxf(mloc[r], __shfl_xor(mloc[r], off, 64));

        // ---- defer-max (T13): rescale only when max grew > THR ----
        bool ok = true;
        #pragma unroll
        for (int r = 0; r < 4; ++r) ok &= (mloc[r] <= m_run[r] + 8.f);
        if (!__all(ok)) {
            float alpha[4];
            #pragma unroll
            for (int r = 0; r < 4; ++r) {
                float mn = fmaxf(m_run[r], mloc[r]);
                alpha[r] = __expf(m_run[r] - mn);
                m_run[r] = mn;
                l_run[r] *= alpha[r];
            }
            #pragma unroll
            for (int dt = 0; dt < 8; ++dt)
                #pragma unroll
                for (int r = 0; r < 4; ++r) oacc[dt][r] *= alpha[r];
        }

        float lloc[4] = {0.f, 0.f, 0.f, 0.f};
        #pragma unroll
        for (int f = 0; f < 4; ++f)
            #pragma unroll
            for (int r = 0; r < 4; ++r) {
                float pe = __expf(sacc[f][r] - m_run[r]);
                sacc[f][r] = pe;              // in place: sacc now holds P
                lloc[r] += pe;
            }
        #pragma unroll
        for (int off = 1; off < 16; off <<= 1)
            #pragma unroll
            for (int r = 0; r < 4; ++r)
                lloc[r] += __shfl_xor(lloc[r], off, 64);
        #pragma unroll
        for (int r = 0; r < 4; ++r) l_run[r] += lloc[r];

        // ---- P (C-layout) -> own LDS rows (wave-private, stride 72) ----
        #pragma unroll
        for (int f = 0; f < 4; ++f)
            #pragma unroll
            for (int r = 0; r < 4; ++r)
                Ps[(wave * 16 + quad * 4 + r) * 72 + f * 16 + l16] =
                    __float2bfloat16(sacc[f][r]);
        // same-wave RAW covered by lgkmcnt; Ps rows are wave-private

        // ---- O += P V ----
        __builtin_amdgcn_s_setprio(1);
        #pragma unroll
        for (int f2 = 0; f2 < 2; ++f2) {
            bf16x8 a = *(const bf16x8*)(
                &Ps[(wave * 16 + l16) * 72 + f2 * 32 + quad * 8]);
            #pragma unroll
            for (int dt = 0; dt < 8; ++dt) {
                bf16x8 b = *(const bf16x8*)(
                    &Vs[f2 * 4096 + (dt * 16 + l16) * 32 + quad * 8]);
                oacc[dt] = MFMA16(a, b, oacc[dt]);
            }
        }
        __builtin_amdgcn_s_setprio(0);
    }

    // epilogue: normalize and store O (bf16) into [B][S][D_MODEL]
    #pragma unroll
    for (int dt = 0; dt < 8; ++dt)
        #pragma unroll
        for (int r = 0; r < 4; ++r) {
            int srow = q0 + wave * 16 + quad * 4 + r;
            float val = oacc[dt][r] / l_run[r];
            o[((size_t)(bb * SEQ + srow)) * DM + hh * DH + dt * 16 + l16] =
                __float2bfloat16(val);
        }
}

// ---------------------------------------------------------------------------
extern "C" void kernel_launch(void* const* d_in, const int* in_sizes, int n_in,
                              void* d_out, int out_size, void* d_ws, size_t ws_size,
                              hipStream_t stream)
{
    const float* x     = (const float*)d_in[0];   // [4,2048,2048] fp32
    const float* w_qkv = (const float*)d_in[1];   // [2048,6144]   fp32
    const float* b_qkv = (const float*)d_in[2];   // [6144]        fp32
    const float* w_out = (const float*)d_in[3];   // [2048,2048]   fp32
    const float* b_out = (const float*)d_in[4];   // [2048]        fp32
    float* out = (float*)d_out;                   // [4,2048,2048] fp32
    __hip_bfloat16* ws = (__hip_bfloat16*)d_ws;

    constexpr size_t NX    = (size_t)MROWS * DM;        // 16.78M
    constexpr size_t NWQKV = (size_t)DM * 3 * DM;       // 12.58M
    constexpr size_t NWOUT = (size_t)DM * DM;           //  4.19M
    constexpr size_t T     = (size_t)BH * SEQ * DH;     // 16.78M

    __hip_bfloat16* xb    = ws;                         // reused as op later
    __hip_bfloat16* wqkvT = ws + NX;
    __hip_bfloat16* woutT = ws + NX + NWQKV;
    __hip_bfloat16* qkv   = ws + NX + NWQKV + NWOUT;    // q | k | v^T
    __hip_bfloat16* op    = xb;                         // [B][S][D] bf16

    // 0) precision/layout prep (memory-bound, ~35 us total)
    cvt_bf16<<<NX / (8 * 256), 256, 0, stream>>>(x, xb);
    cvt_T<<<dim3(3 * DM / 32, DM / 32), 256, 0, stream>>>(w_qkv, wqkvT, DM, 3 * DM);
    cvt_T<<<dim3(DM / 32, DM / 32), 256, 0, stream>>>(w_out, woutT, DM, DM);

    // 1) fused QKV projection -> q,k [BH][S][Dh], v [BH][Dh][S]
    gemm_bt256<0><<<dim3(3 * DM / 256, MROWS / 256), 512, 0, stream>>>(
        xb, wqkvT, b_qkv, qkv, DM);
    // 2) causal flash attention (descending-qt order, 3 blocks/CU)
    attn_kernel<<<dim3(16, BH), 512, 0, stream>>>(
        qkv, qkv + T, qkv + 2 * T, op);
    // 3) output projection -> fp32 d_out
    gemm_bt256<1><<<dim3(DM / 256, MROWS / 256), 512, 0, stream>>>(
        op, woutT, b_out, out, DM);
}

// Round 9
// 569.410 us; speedup vs baseline: 2.3625x; 1.0914x over previous
//
#include <hip/hip_runtime.h>
#include <hip/hip_bf16.h>

typedef short bf16x8 __attribute__((ext_vector_type(8)));   // 8 bf16 in 4 VGPRs
typedef float f32x4  __attribute__((ext_vector_type(4)));   // MFMA C/D frag

#define MFMA16(a,b,c) __builtin_amdgcn_mfma_f32_16x16x32_bf16((a),(b),(c),0,0,0)

typedef __attribute__((address_space(3))) unsigned int       lds_u32;
typedef const __attribute__((address_space(1))) unsigned int g_u32;

static constexpr int SEQ = 2048;
static constexpr int DM  = 2048;
static constexpr int NH  = 16;
static constexpr int DH  = 128;
static constexpr int BAT = 4;
static constexpr int BH  = BAT * NH;      // 64
static constexpr int MROWS = BAT * SEQ;   // 8192

// ---------------------------------------------------------------------------
// fp32 -> bf16 elementwise (8 elems/thread, 16B loads, 16B stores)
// ---------------------------------------------------------------------------
__global__ __launch_bounds__(256)
void cvt_bf16(const float* __restrict__ in, __hip_bfloat16* __restrict__ out)
{
    int i = blockIdx.x * 256 + threadIdx.x;
    const float4* p = (const float4*)in + (size_t)i * 2;
    float4 a = p[0], b = p[1];
    __hip_bfloat16 t[8];
    t[0]=__float2bfloat16(a.x); t[1]=__float2bfloat16(a.y);
    t[2]=__float2bfloat16(a.z); t[3]=__float2bfloat16(a.w);
    t[4]=__float2bfloat16(b.x); t[5]=__float2bfloat16(b.y);
    t[6]=__float2bfloat16(b.z); t[7]=__float2bfloat16(b.w);
    *(uint4*)(out + (size_t)i * 8) = *(uint4*)t;
}

// ---------------------------------------------------------------------------
// fp32 [K][N] -> bf16 [N][K] transpose-convert, 32x32 LDS tiles
// ---------------------------------------------------------------------------
__global__ __launch_bounds__(256)
void cvt_T(const float* __restrict__ in, __hip_bfloat16* __restrict__ out,
           int K, int N)
{
    __shared__ float t[32][33];
    const int n0 = blockIdx.x * 32, k0 = blockIdx.y * 32;
    const int r = threadIdx.x >> 3, c4 = (threadIdx.x & 7) * 4;
    float4 v = *(const float4*)(in + (size_t)(k0 + r) * N + n0 + c4);
    t[r][c4] = v.x; t[r][c4+1] = v.y; t[r][c4+2] = v.z; t[r][c4+3] = v.w;
    __syncthreads();
    __hip_bfloat16 o[4];
    #pragma unroll
    for (int j = 0; j < 4; ++j) o[j] = __float2bfloat16(t[c4 + j][r]);
    *(uint2*)(out + (size_t)(n0 + r) * K + k0 + c4) = *(uint2*)o;
}

// ---------------------------------------------------------------------------
// Stage one half-tile (128 rows x 64 k, bf16) into LDS via global_load_lds.
// LDS dest is LINEAR; XOR-swizzle (chunk' = k8 ^ (row&7)) applied by
// pre-swizzling the per-lane GLOBAL source address (rule #21).
// ---------------------------------------------------------------------------
__device__ __forceinline__
void stage_half(const __hip_bfloat16* __restrict__ g, int row0, int k0, int K,
                __hip_bfloat16* l, int tid)
{
    #pragma unroll
    for (int pass = 0; pass < 2; ++pass) {
        int c   = pass * 512 + tid;              // chunk index within half
        int row = c >> 3;                        // 0..127
        int k8  = (c & 7) ^ (row & 7);           // inverse-swizzled k-octet
        const __hip_bfloat16* gp = g + (size_t)(row0 + row) * K + k0 + k8 * 8;
        __hip_bfloat16* lp = l + (size_t)(pass * 512 + (tid & ~63)) * 8;
        __builtin_amdgcn_global_load_lds((g_u32*)gp, (lds_u32*)lp, 16, 0, 0);
    }
}

// ---------------------------------------------------------------------------
// 256x256-tile 8-phase GEMM, BK=64, 8 waves (2M x 4N), 512 threads,
// 128 KiB LDS (2 tile dbuf x (A,B), XOR-swz).
// r9: schedule REVERTED to the r7 variant (within-session A/B: r7 246.5us
// vs r8 254.8 — r8's phase-4 double-stage burst backed up the memory queue
// right before its drain; smooth 2-loads-per-phase issue wins):
//   p1: ds afl+bf01; stage A0(t+1)->other buf
//   p2: ds bf23;     stage A1(t+1)->other buf
//   p3: ds afh;      stage B0(t+2)->own buf (B read done @p2)
//   p4:              stage B1(t+2); vmcnt(4); barrier; MFMA; barrier
// Block order: XCD-chunked, m-fast half-stripes of 2 (r7).
// MODE 0 epilogue: V stores packed 4xbf16 -> one 8B store (consecutive r
// are address-consecutive for the V^T layout).
// ---------------------------------------------------------------------------
template<int MODE>
__global__ __launch_bounds__(512)
void gemm_bt256(const __hip_bfloat16* __restrict__ A,
                const __hip_bfloat16* __restrict__ Bt,
                const float* __restrict__ bias,
                void* __restrict__ outp, int K)
{
    __shared__ __hip_bfloat16 As[2][16384];   // [buf][row*8 + k8] chunks
    __shared__ __hip_bfloat16 Bs[2][16384];

    const int tid  = threadIdx.x;
    const int wave = tid >> 6, lane = tid & 63;
    const int quad = lane >> 4, l16 = lane & 15;
    const int wr = wave >> 2, wc = wave & 3;   // 2 x 4 wave grid

    const int bid  = blockIdx.y * gridDim.x + blockIdx.x;
    const int xcd  = bid & 7, local = bid >> 3;
    const int mpx  = gridDim.y >> 3;           // 4 for both call sites
    const int sub  = local / (gridDim.x * 2);
    const int rem  = local % (gridDim.x * 2);
    const int n0   = (rem >> 1) * 256;
    const int m0   = (xcd * mpx + sub * 2 + (rem & 1)) * 256;

    const int NT = K >> 6;                     // 64-wide K tiles
    const int swz = l16 & 7;                   // per-lane read-side XOR

    f32x4 acc[8][4] = {};

    stage_half(A,  m0,        0,  K, &As[0][0],    tid);
    stage_half(A,  m0 + 128,  0,  K, &As[0][8192], tid);
    stage_half(Bt, n0,        0,  K, &Bs[0][0],    tid);
    stage_half(Bt, n0 + 128,  0,  K, &Bs[0][8192], tid);
    stage_half(Bt, n0,        64, K, &Bs[1][0],    tid);
    stage_half(Bt, n0 + 128,  64, K, &Bs[1][8192], tid);
    asm volatile("s_waitcnt vmcnt(4)" ::: "memory");
    __builtin_amdgcn_s_barrier();

    for (int t = 0; t < NT; ++t) {
        const int cur = t & 1;
        const char* Ab = (const char*)&As[cur][0];
        const char* Bb = (const char*)&Bs[cur][0];
        bf16x8 afl[4][2], afh[4][2], bf[4][2];

        // ================= phase 1 =================
        #pragma unroll
        for (int i = 0; i < 4; ++i)
            #pragma unroll
            for (int kk = 0; kk < 2; ++kk)
                afl[i][kk] = *(const bf16x8*)(Ab + (wr*128 + i*16 + l16)*128
                              + ((((kk<<2)|quad) ^ swz) << 4));
        #pragma unroll
        for (int j = 0; j < 2; ++j)
            #pragma unroll
            for (int kk = 0; kk < 2; ++kk)
                bf[j][kk] = *(const bf16x8*)(Bb + (wc*64 + j*16 + l16)*128
                              + ((((kk<<2)|quad) ^ swz) << 4));
        if (t + 1 < NT)
            stage_half(A, m0, (t+1)*64, K, &As[cur^1][0], tid);
        __builtin_amdgcn_s_barrier();
        asm volatile("s_waitcnt lgkmcnt(0)" ::: "memory");
        __builtin_amdgcn_s_setprio(1);
        #pragma unroll
        for (int i = 0; i < 4; ++i)
            #pragma unroll
            for (int j = 0; j < 2; ++j) {
                acc[i][j] = MFMA16(afl[i][0], bf[j][0], acc[i][j]);
                acc[i][j] = MFMA16(afl[i][1], bf[j][1], acc[i][j]);
            }
        __builtin_amdgcn_s_setprio(0);
        __builtin_amdgcn_s_barrier();

        // ================= phase 2 =================
        #pragma unroll
        for (int j = 2; j < 4; ++j)
            #pragma unroll
            for (int kk = 0; kk < 2; ++kk)
                bf[j][kk] = *(const bf16x8*)(Bb + (wc*64 + j*16 + l16)*128
                              + ((((kk<<2)|quad) ^ swz) << 4));
        if (t + 1 < NT)
            stage_half(A, m0 + 128, (t+1)*64, K, &As[cur^1][8192], tid);
        __builtin_amdgcn_s_barrier();
        asm volatile("s_waitcnt lgkmcnt(0)" ::: "memory");
        __builtin_amdgcn_s_setprio(1);
        #pragma unroll
        for (int i = 0; i < 4; ++i)
            #pragma unroll
            for (int j = 2; j < 4; ++j) {
                acc[i][j] = MFMA16(afl[i][0], bf[j][0], acc[i][j]);
                acc[i][j] = MFMA16(afl[i][1], bf[j][1], acc[i][j]);
            }
        __builtin_amdgcn_s_setprio(0);
        __builtin_amdgcn_s_barrier();

        // ================= phase 3 =================
        #pragma unroll
        for (int i = 0; i < 4; ++i)
            #pragma unroll
            for (int kk = 0; kk < 2; ++kk)
                afh[i][kk] = *(const bf16x8*)(Ab + (wr*128 + (4+i)*16 + l16)*128
                              + ((((kk<<2)|quad) ^ swz) << 4));
        if (t + 2 < NT)
            stage_half(Bt, n0, (t+2)*64, K, &Bs[cur][0], tid);
        __builtin_amdgcn_s_barrier();
        asm volatile("s_waitcnt lgkmcnt(0)" ::: "memory");
        __builtin_amdgcn_s_setprio(1);
        #pragma unroll
        for (int i = 0; i < 4; ++i)
            #pragma unroll
            for (int j = 0; j < 2; ++j) {
                acc[4+i][j] = MFMA16(afh[i][0], bf[j][0], acc[4+i][j]);
                acc[4+i][j] = MFMA16(afh[i][1], bf[j][1], acc[4+i][j]);
            }
        __builtin_amdgcn_s_setprio(0);
        __builtin_amdgcn_s_barrier();

        // ================= phase 4 =================
        if (t + 2 < NT)
            stage_half(Bt, n0 + 128, (t+2)*64, K, &Bs[cur][8192], tid);
        asm volatile("s_waitcnt vmcnt(4)" ::: "memory");  // (t+1) halves landed
        __builtin_amdgcn_s_barrier();
        __builtin_amdgcn_s_setprio(1);
        #pragma unroll
        for (int i = 0; i < 4; ++i)
            #pragma unroll
            for (int j = 2; j < 4; ++j) {
                acc[4+i][j] = MFMA16(afh[i][0], bf[j][0], acc[4+i][j]);
                acc[4+i][j] = MFMA16(afh[i][1], bf[j][1], acc[4+i][j]);
            }
        __builtin_amdgcn_s_setprio(0);
        __builtin_amdgcn_s_barrier();
    }

    // ---- epilogue: D row = quad*4+r, col = l16 (m89/m91 layout) ----
    #pragma unroll
    for (int i = 0; i < 8; ++i)
        #pragma unroll
        for (int j = 0; j < 4; ++j) {
            int col = n0 + wc * 64 + j * 16 + l16;
            float bs = bias[col];
            if (MODE == 0) {
                int which = col >> 11, h = (col >> 7) & 15, d = col & 127;
                int row0 = m0 + wr * 128 + i * 16 + quad * 4;
                int bb = row0 >> 11, s0 = row0 & 2047;
                __hip_bfloat16* o = (__hip_bfloat16*)outp;
                if (which == 2) {
                    // V^T [BH][Dh][S]: consecutive r -> consecutive s ->
                    // pack 4 bf16 into one 8B store
                    __hip_bfloat16 t4[4];
                    #pragma unroll
                    for (int r = 0; r < 4; ++r)
                        t4[r] = __float2bfloat16(acc[i][j][r] + bs);
                    size_t idx = 2 * (size_t)BH * SEQ * DH +
                                 ((size_t)(bb * NH + h) * DH + d) * SEQ + s0;
                    *(uint2*)(o + idx) = *(const uint2*)t4;
                } else {
                    #pragma unroll
                    for (int r = 0; r < 4; ++r) {
                        size_t idx = (size_t)which * BH * SEQ * DH +
                                     ((size_t)(bb * NH + h) * SEQ + s0 + r) * DH + d;
                        o[idx] = __float2bfloat16(acc[i][j][r] + bs);
                    }
                }
            } else {
                #pragma unroll
                for (int r = 0; r < 4; ++r) {
                    int row = m0 + wr * 128 + i * 16 + quad * 4 + r;
                    ((float*)outp)[(size_t)row * DM + col] = acc[i][j][r] + bs;
                }
            }
        }
}

// ---------------------------------------------------------------------------
// Causal flash attention, 8-wave / 128 q-rows, ONE q-tile per block,
// grid 1024 ordered by DESCENDING qt; 3 blocks/CU (50 KB LDS).
// r9 changes vs r8:
//  * K/V LDS are row-major ([64][128] / [128][64]) with chunk-XOR swizzle
//    (chunk ^= row&7) applied via inverse-swizzled GLOBAL source (rule #21)
//    and swizzled frag reads.  Staging global pattern becomes contiguous
//    256B (K) / 128B (V) runs per wave instead of 64B clumps -> fewer L2
//    requests per stage instruction.  Reads are 2-way bank-aliased (free).
//  * exp2-domain softmax: Q prescaled by scale*log2e; __expf -> exp2f
//    (single v_exp_f32); defer-max THR 8 nat -> 11 log2.
// XCD remap keeps each XCD on 8 heads (K/V L2-resident).
// ---------------------------------------------------------------------------
__global__ __launch_bounds__(512)
void attn_kernel(const __hip_bfloat16* __restrict__ q,
                 const __hip_bfloat16* __restrict__ k,
                 const __hip_bfloat16* __restrict__ v,
                 __hip_bfloat16* __restrict__ o)
{
    __shared__ __hip_bfloat16 Ks[64 * 128];       // 16 KB: [kcol][dh] swz
    __shared__ __hip_bfloat16 Vs[128 * 64];       // 16 KB: [d][s] swz
    __shared__ __hip_bfloat16 Ps[128 * 72];       // 18 KB: [qrow][72]

    const int tid  = threadIdx.x;
    const int wave = tid >> 6, lane = tid & 63;
    const int quad = lane >> 4, l16 = lane & 15;
    const int swz = l16 & 7;

    // grid = dim3(16, 64) -> bid in [0,1024); xcd = bid&7 owns 8 heads;
    // qt descends with bid so the work-heavy blocks dispatch first.
    const int bid = blockIdx.y * gridDim.x + blockIdx.x;
    const int bh  = (bid & 7) * 8 + ((bid >> 3) & 7);
    const int qt  = 15 - (bid >> 6);
    const int q0  = qt * 128;
    const int nkt = 2 * qt + 2;                   // k-tiles covering q0+127
    const size_t base = (size_t)bh * SEQ * DH;    // same elem count for V^T
    const float scale2 = 0.08838834764831845f * 1.4426950408889634f; // /sqrt(128)*log2e
    const int bb = bh >> 4, hh = bh & 15;

    // Q fragments in registers, prescaled (exp2 domain): A[m=l16][k=quad*8+j]
    bf16x8 qf[4];
    #pragma unroll
    for (int kk = 0; kk < 4; ++kk) {
        bf16x8 raw = *(const bf16x8*)(
            q + base + (size_t)(q0 + wave * 16 + l16) * DH + kk * 32 + quad * 8);
        #pragma unroll
        for (int jj = 0; jj < 8; ++jj) {
            __hip_bfloat16 h = ((const __hip_bfloat16*)&raw)[jj];
            ((__hip_bfloat16*)&qf[kk])[jj] =
                __float2bfloat16(__bfloat162float(h) * scale2);
        }
    }

    float m_run[4], l_run[4];
    f32x4 oacc[8] = {};
    #pragma unroll
    for (int r = 0; r < 4; ++r) { m_run[r] = -1e30f; l_run[r] = 0.f; }

    const int wmax = q0 + wave * 16 + 15;         // last unmasked row of wave

    for (int kt = 0; kt < nkt; ++kt) {
        __syncthreads();   // prior iter's Ks/Vs reads done
        // ---- DMA-stage K tile [64][128] + V^T tile [128][64], XOR-swz ----
        {
            const __hip_bfloat16* kbase = k + base + (size_t)(kt * 64) * DH;
            const __hip_bfloat16* vbase = v + base + kt * 64;
            #pragma unroll
            for (int p = 0; p < 2; ++p) {
                int c = p * 512 + tid;                 // chunk id = LDS/16B
                int krow = c >> 4, kc = (c & 15) ^ (krow & 7);
                const __hip_bfloat16* gk = kbase + (size_t)krow * DH + kc * 8;
                __hip_bfloat16* lk = Ks + (size_t)(p * 512 + (tid & ~63)) * 8;
                __builtin_amdgcn_global_load_lds((g_u32*)gk, (lds_u32*)lk, 16, 0, 0);
                int vd = c >> 3, vc = (c & 7) ^ (vd & 7);
                const __hip_bfloat16* gv = vbase + (size_t)vd * SEQ + vc * 8;
                __hip_bfloat16* lv = Vs + (size_t)(p * 512 + (tid & ~63)) * 8;
                __builtin_amdgcn_global_load_lds((g_u32*)gv, (lds_u32*)lv, 16, 0, 0);
            }
        }
        __syncthreads();   // staging visible (vmcnt drain + barrier)

        if (kt * 64 > wmax) continue;   // wave fully masked for this tile

        // ---- S = (Q*scale) K^T : 16 q rows x 64 k cols per wave ----
        f32x4 sacc[4] = {};
        __builtin_amdgcn_s_setprio(1);
        #pragma unroll
        for (int kk = 0; kk < 4; ++kk)
            #pragma unroll
            for (int f = 0; f < 4; ++f) {
                bf16x8 b = *(const bf16x8*)(
                    &Ks[(f * 16 + l16) * 128 + ((((kk << 2) | quad) ^ swz) << 3)]);
                sacc[f] = MFMA16(qf[kk], b, sacc[f]);
            }
        __builtin_amdgcn_s_setprio(0);

        // ---- causal mask (diagonal tiles only) + online softmax ----
        const int qrow = q0 + wave * 16 + quad * 4;
        if (kt * 64 + 63 > q0 + wave * 16) {
            #pragma unroll
            for (int f = 0; f < 4; ++f)
                #pragma unroll
                for (int r = 0; r < 4; ++r) {
                    int kg = kt * 64 + f * 16 + l16;
                    if (kg > qrow + r) sacc[f][r] = -1e30f;
                }
        }
        float mloc[4] = {-1e30f, -1e30f, -1e30f, -1e30f};
        #pragma unroll
        for (int f = 0; f < 4; ++f)
            #pragma unroll
            for (int r = 0; r < 4; ++r)
                mloc[r] = fmaxf(mloc[r], sacc[f][r]);
        #pragma unroll
        for (int off = 1; off < 16; off <<= 1)
            #pragma unroll
            for (int r = 0; r < 4; ++r)
                mloc[r] = fmaxf(mloc[r], __shfl_xor(mloc[r], off, 64));

        // ---- defer-max (T13, log2 domain): rescale only when max grew ----
        bool ok = true;
        #pragma unroll
        for (int r = 0; r < 4; ++r) ok &= (mloc[r] <= m_run[r] + 11.f);
        if (!__all(ok)) {
            float alpha[4];
            #pragma unroll
            for (int r = 0; r < 4; ++r) {
                float mn = fmaxf(m_run[r], mloc[r]);
                alpha[r] = exp2f(m_run[r] - mn);
                m_run[r] = mn;
                l_run[r] *= alpha[r];
            }
            #pragma unroll
            for (int dt = 0; dt < 8; ++dt)
                #pragma unroll
                for (int r = 0; r < 4; ++r) oacc[dt][r] *= alpha[r];
        }

        float lloc[4] = {0.f, 0.f, 0.f, 0.f};
        #pragma unroll
        for (int f = 0; f < 4; ++f)
            #pragma unroll
            for (int r = 0; r < 4; ++r) {
                float pe = exp2f(sacc[f][r] - m_run[r]);
                sacc[f][r] = pe;              // in place: sacc now holds P
                lloc[r] += pe;
            }
        #pragma unroll
        for (int off = 1; off < 16; off <<= 1)
            #pragma unroll
            for (int r = 0; r < 4; ++r)
                lloc[r] += __shfl_xor(lloc[r], off, 64);
        #pragma unroll
        for (int r = 0; r < 4; ++r) l_run[r] += lloc[r];

        // ---- P (C-layout) -> own LDS rows (wave-private, stride 72) ----
        #pragma unroll
        for (int f = 0; f < 4; ++f)
            #pragma unroll
            for (int r = 0; r < 4; ++r)
                Ps[(wave * 16 + quad * 4 + r) * 72 + f * 16 + l16] =
                    __float2bfloat16(sacc[f][r]);
        // same-wave RAW covered by lgkmcnt; Ps rows are wave-private

        // ---- O += P V ----
        __builtin_amdgcn_s_setprio(1);
        #pragma unroll
        for (int f2 = 0; f2 < 2; ++f2) {
            bf16x8 a = *(const bf16x8*)(
                &Ps[(wave * 16 + l16) * 72 + f2 * 32 + quad * 8]);
            #pragma unroll
            for (int dt = 0; dt < 8; ++dt) {
                bf16x8 b = *(const bf16x8*)(
                    &Vs[(dt * 16 + l16) * 64 + ((((f2 << 2) | quad) ^ swz) << 3)]);
                oacc[dt] = MFMA16(a, b, oacc[dt]);
            }
        }
        __builtin_amdgcn_s_setprio(0);
    }

    // epilogue: normalize and store O (bf16) into [B][S][D_MODEL]
    #pragma unroll
    for (int dt = 0; dt < 8; ++dt)
        #pragma unroll
        for (int r = 0; r < 4; ++r) {
            int srow = q0 + wave * 16 + quad * 4 + r;
            float val = oacc[dt][r] / l_run[r];
            o[((size_t)(bb * SEQ + srow)) * DM + hh * DH + dt * 16 + l16] =
                __float2bfloat16(val);
        }
}

// ---------------------------------------------------------------------------
extern "C" void kernel_launch(void* const* d_in, const int* in_sizes, int n_in,
                              void* d_out, int out_size, void* d_ws, size_t ws_size,
                              hipStream_t stream)
{
    const float* x     = (const float*)d_in[0];   // [4,2048,2048] fp32
    const float* w_qkv = (const float*)d_in[1];   // [2048,6144]   fp32
    const float* b_qkv = (const float*)d_in[2];   // [6144]        fp32
    const float* w_out = (const float*)d_in[3];   // [2048,2048]   fp32
    const float* b_out = (const float*)d_in[4];   // [2048]        fp32
    float* out = (float*)d_out;                   // [4,2048,2048] fp32
    __hip_bfloat16* ws = (__hip_bfloat16*)d_ws;

    constexpr size_t NX    = (size_t)MROWS * DM;        // 16.78M
    constexpr size_t NWQKV = (size_t)DM * 3 * DM;       // 12.58M
    constexpr size_t NWOUT = (size_t)DM * DM;           //  4.19M
    constexpr size_t T     = (size_t)BH * SEQ * DH;     // 16.78M

    __hip_bfloat16* xb    = ws;                         // reused as op later
    __hip_bfloat16* wqkvT = ws + NX;
    __hip_bfloat16* woutT = ws + NX + NWQKV;
    __hip_bfloat16* qkv   = ws + NX + NWQKV + NWOUT;    // q | k | v^T
    __hip_bfloat16* op    = xb;                         // [B][S][D] bf16

    // 0) precision/layout prep (memory-bound, ~35 us total)
    cvt_bf16<<<NX / (8 * 256), 256, 0, stream>>>(x, xb);
    cvt_T<<<dim3(3 * DM / 32, DM / 32), 256, 0, stream>>>(w_qkv, wqkvT, DM, 3 * DM);
    cvt_T<<<dim3(DM / 32, DM / 32), 256, 0, stream>>>(w_out, woutT, DM, DM);

    // 1) fused QKV projection -> q,k [BH][S][Dh], v [BH][Dh][S]
    gemm_bt256<0><<<dim3(3 * DM / 256, MROWS / 256), 512, 0, stream>>>(
        xb, wqkvT, b_qkv, qkv, DM);
    // 2) causal flash attention (descending-qt order, 3 blocks/CU)
    attn_kernel<<<dim3(16, BH), 512, 0, stream>>>(
        qkv, qkv + T, qkv + 2 * T, op);
    // 3) output projection -> fp32 d_out
    gemm_bt256<1><<<dim3(DM / 256, MROWS / 256), 512, 0, stream>>>(
        op, woutT, b_out, out, DM);
}